// Round 7
// baseline (971.894 us; speedup 1.0000x reference)
//
#include <hip/hip_runtime.h>
#include <hip/hip_bf16.h>

#define NN 49152
#define GG 1024
#define EE 65536
#define ETOT 196608
#define FF 384
#define NEG_SLOPE 0.2f

typedef __attribute__((ext_vector_type(8))) short bf16x8;
typedef __attribute__((ext_vector_type(4))) float f32x4;

__device__ __forceinline__ float wave_sum(float v) {
#pragma unroll
    for (int m = 32; m; m >>= 1) v += __shfl_xor(v, m);
    return v;
}
__device__ __forceinline__ unsigned short f2bf(float f) {
    __hip_bfloat16 b = __float2bfloat16(f);
    return *reinterpret_cast<unsigned short*>(&b);
}
__device__ __forceinline__ float bflo(unsigned u) { return __uint_as_float(u << 16); }
__device__ __forceinline__ float bfhi(unsigned u) { return __uint_as_float(u & 0xffff0000u); }

__device__ __forceinline__ void gload_lds16(const void* g, void* l) {
    __builtin_amdgcn_global_load_lds(
        (const __attribute__((address_space(1))) unsigned int*)g,
        (__attribute__((address_space(3))) unsigned int*)l, 16, 0, 0);
}

// ================= MFMA bf16 GEMM: C = act(A @ Bt^T + bias) =================
// Physical LDS convention: position (row, c) holds logical chunk c ^ ((row>>1)&3).
__device__ __forceinline__ int swz(int row, int c16) {
    return row * 64 + ((c16 ^ ((row >> 1) & 3)) << 4);
}

template <int ACT, bool ABF, bool OBF>
__global__ __launch_bounds__(256) void gemm_mfma(
    const void* __restrict__ Ag, int K,
    const unsigned short* __restrict__ Btg,
    const float* __restrict__ bias,
    void* __restrict__ Cg, int ldc,
    size_t bzs, size_t czs)
{
    __shared__ __align__(16) char As[8192];
    __shared__ __align__(16) char Bs[8192];
    const unsigned short* Bt = Btg + (size_t)blockIdx.z * bzs;
    int t = threadIdx.x;
    int bm = blockIdx.y << 7, bn = blockIdx.x << 7;
    int lane = t & 63, wid = t >> 6, wr = wid >> 1, wc = wid & 1;
    f32x4 acc[4][4] = {};
    int ktn = K >> 5;
    for (int kt = 0; kt < ktn; ++kt) {
        int k0 = kt << 5;
#pragma unroll
        for (int ii = 0; ii < 2; ++ii) {
            int id = t + (ii << 8);
            int row = id >> 2, c = id & 3;
            int csrc = c ^ ((row >> 1) & 3);  // pre-swizzled source chunk
            size_t ldsoff = (size_t)((wid << 10) + (ii << 12));  // wave-uniform offset
            if (ABF) {
                const unsigned short* srcA = (const unsigned short*)Ag + (size_t)(bm + row) * K + k0 + csrc * 8;
                gload_lds16(srcA, As + ldsoff);
            } else {
                const float* srcA = (const float*)Ag + (size_t)(bm + row) * K + k0 + c * 8;
                float4 a0 = *(const float4*)srcA;
                float4 a1 = *(const float4*)(srcA + 4);
                union { unsigned short u[8]; int4 v; } P;
                P.u[0] = f2bf(a0.x); P.u[1] = f2bf(a0.y); P.u[2] = f2bf(a0.z); P.u[3] = f2bf(a0.w);
                P.u[4] = f2bf(a1.x); P.u[5] = f2bf(a1.y); P.u[6] = f2bf(a1.z); P.u[7] = f2bf(a1.w);
                *(int4*)(As + swz(row, c)) = P.v;
            }
            const unsigned short* srcB = Bt + (size_t)(bn + row) * K + k0 + csrc * 8;
            gload_lds16(srcB, Bs + ldsoff);
        }
        __syncthreads();
        int c16 = lane >> 4;
        bf16x8 af[4], bfr[4];
#pragma unroll
        for (int m = 0; m < 4; ++m)
            af[m] = *(const bf16x8*)(As + swz((wr << 6) + (m << 4) + (lane & 15), c16));
#pragma unroll
        for (int n = 0; n < 4; ++n)
            bfr[n] = *(const bf16x8*)(Bs + swz((wc << 6) + (n << 4) + (lane & 15), c16));
#pragma unroll
        for (int m = 0; m < 4; ++m)
#pragma unroll
            for (int n = 0; n < 4; ++n)
                acc[m][n] = __builtin_amdgcn_mfma_f32_16x16x32_bf16(af[m], bfr[n], acc[m][n], 0, 0, 0);
        __syncthreads();
    }
#pragma unroll
    for (int m = 0; m < 4; ++m) {
#pragma unroll
        for (int n = 0; n < 4; ++n) {
            int row0 = bm + (wr << 6) + (m << 4) + ((lane >> 4) << 2);
            int col = bn + (wc << 6) + (n << 4) + (lane & 15);
            float bv = bias ? bias[col] : 0.f;
#pragma unroll
            for (int j = 0; j < 4; ++j) {
                float v = acc[m][n][j] + bv;
                if (ACT == 1) v = fmaxf(v, 0.f);
                if (OBF) {
                    unsigned short* C = (unsigned short*)Cg + (size_t)blockIdx.z * czs;
                    C[(size_t)(row0 + j) * ldc + col] = f2bf(v);
                } else {
                    float* C = (float*)Cg + (size_t)blockIdx.z * czs;
                    C[(size_t)(row0 + j) * ldc + col] = v;
                }
            }
        }
    }
}

// ================= f32 fallback GEMM (small K / small N), z-batched A =================
template <int ACT>
__global__ __launch_bounds__(256) void gemm_k(
    const float* __restrict__ Ag, int K,
    const float* __restrict__ Wg, int Jw,
    const float* __restrict__ bias,
    float* __restrict__ Cg, int ldc, int jmax,
    size_t wzs, size_t czs, size_t azs)
{
    __shared__ float Ash[16][64];
    __shared__ float Bsh[16][68];
    const float* A = Ag + (size_t)blockIdx.z * azs;
    const float* W = Wg + (size_t)blockIdx.z * wzs;
    float* C = Cg + (size_t)blockIdx.z * czs;
    int tid = threadIdx.x;
    int bj = blockIdx.x << 6;
    int bm = blockIdx.y << 6;
    int tx = tid & 15, ty = tid >> 4;
    float acc[4][4] = {};
    int ktn = (K + 15) >> 4;
    int ar = tid >> 2;
    int aks = (tid & 3) << 2;
    int wk = tid >> 4;
    int wjs = (tid & 15) << 2;
    for (int kt = 0; kt < ktn; ++kt) {
        int k0 = kt << 4;
        const float* Ap = A + (size_t)(bm + ar) * K + k0 + aks;
#pragma unroll
        for (int i = 0; i < 4; ++i) {
            int k = k0 + aks + i;
            Ash[aks + i][ar] = (k < K) ? Ap[i] : 0.f;
        }
        const float* Wp = W + (size_t)(k0 + wk) * Jw + bj + wjs;
        bool kok = (k0 + wk) < K;
#pragma unroll
        for (int i = 0; i < 4; ++i) {
            int j = bj + wjs + i;
            Bsh[wk][wjs + i] = (kok && j < jmax) ? Wp[i] : 0.f;
        }
        __syncthreads();
#pragma unroll
        for (int kk = 0; kk < 16; ++kk) {
            const float4 av = *reinterpret_cast<const float4*>(&Ash[kk][ty << 2]);
            const float4 bv = *reinterpret_cast<const float4*>(&Bsh[kk][tx << 2]);
            float aa[4] = {av.x, av.y, av.z, av.w};
            float bb[4] = {bv.x, bv.y, bv.z, bv.w};
#pragma unroll
            for (int i = 0; i < 4; ++i)
#pragma unroll
                for (int j = 0; j < 4; ++j)
                    acc[i][j] = fmaf(aa[i], bb[j], acc[i][j]);
        }
        __syncthreads();
    }
#pragma unroll
    for (int i = 0; i < 4; ++i) {
        int row = bm + (ty << 2) + i;
#pragma unroll
        for (int j = 0; j < 4; ++j) {
            int col = bj + (tx << 2) + j;
            if (col < jmax) {
                float v = acc[i][j];
                if (bias) v += bias[col];
                if (ACT == 1) v = fmaxf(v, 0.f);
                C[(size_t)row * ldc + col] = v;
            }
        }
    }
}

// ================= weight transpose + bf16 convert: Wt[z][n][k] = W[z][k][n] =================
__global__ void transpose_bf(const float* __restrict__ W, unsigned short* __restrict__ Wt,
                             int K, int N, int total) {
    int i = blockIdx.x * 256 + threadIdx.x;
    if (i >= total) return;
    int kn = K * N;
    int z = i / kn, rem = i - z * kn;
    int k = rem / N, n = rem - k * N;
    Wt[(size_t)z * kn + (size_t)n * K + k] = f2bf(W[i]);
}

// pack Wq/Wk f32 [3][384][8] -> wqkt bf16 [48][384], row j = r*16 + qk*8 + h
__global__ void qkw_pack(const float* __restrict__ wq, const float* __restrict__ wk,
                         unsigned short* __restrict__ out) {
    int i = blockIdx.x * 256 + threadIdx.x;
    if (i >= 48 * 384) return;
    int j = i / 384, f = i - j * 384;
    int r = j >> 4, rem = j & 15, qk = rem >> 3, h = rem & 7;
    const float* src = qk ? wk : wq;
    out[i] = f2bf(src[r * 3072 + f * 8 + h]);
}

// ================= CSR build =================
__global__ void csr_count(const int* __restrict__ eo, const int* __restrict__ ea,
                          const int* __restrict__ es, int* __restrict__ deg) {
    int e = blockIdx.x * 256 + threadIdx.x;
    if (e >= ETOT) return;
    int et = e >> 16, le = e & 65535;
    const int* ei = et == 0 ? eo : (et == 1 ? ea : es);
    atomicAdd(&deg[ei[EE + le]], 1);
}
__global__ void csr_alloc(const int* __restrict__ deg, int* __restrict__ counter,
                          int* __restrict__ rps) {
    int n = blockIdx.x * 256 + threadIdx.x;
    int lane = threadIdx.x & 63;
    int d = (n < NN) ? deg[n] : 0;
    int x = d;
#pragma unroll
    for (int off = 1; off < 64; off <<= 1) {
        int y = __shfl_up(x, off);
        if (lane >= off) x += y;
    }
    int total = __shfl(x, 63);
    int base = 0;
    if (lane == 63) base = atomicAdd(counter, total);
    base = __shfl(base, 63);
    if (n < NN) rps[n] = base + x - d;
}
__global__ void csr_fill(const int* __restrict__ eo, const int* __restrict__ ea,
                         const int* __restrict__ es, const int* __restrict__ rps,
                         int* __restrict__ fill, int* __restrict__ elist) {
    int e = blockIdx.x * 256 + threadIdx.x;
    if (e >= ETOT) return;
    int et = e >> 16, le = e & 65535;
    const int* ei = et == 0 ? eo : (et == 1 ? ea : es);
    int src = ei[le], dst = ei[EE + le];
    int pos = rps[dst] + atomicAdd(&fill[dst], 1);
    elist[pos] = (et << 16) | src;
}

// ================= misc =================
__global__ void count_nodes(const int* __restrict__ batch, float* __restrict__ gcnt) {
    int n = blockIdx.x * 256 + threadIdx.x;
    if (n < NN) atomicAdd(&gcnt[batch[n]], 1.f);
}

// ================= encoder stats: two-stage, no atomics =================
#define ERB 512
__global__ __launch_bounds__(256) void enc_reduce_stage1(const float* __restrict__ h0, float* __restrict__ pbuf) {
    __shared__ float part[4][6];
    float a1 = 0.f, a2 = 0.f, b1 = 0.f, b2 = 0.f, c1 = 0.f, c2 = 0.f;
    const float4* h4 = (const float4*)h0;
    int total4 = NN * FF / 4;
    for (int i = blockIdx.x * 256 + threadIdx.x; i < total4; i += ERB * 256) {
        float4 v = h4[i];
        float s1 = v.x + v.y + v.z + v.w;
        float s2 = v.x * v.x + v.y * v.y + v.z * v.z + v.w * v.w;
        int enc = (i % 96) >> 5;
        if (enc == 0)      { a1 += s1; a2 += s2; }
        else if (enc == 1) { b1 += s1; b2 += s2; }
        else               { c1 += s1; c2 += s2; }
    }
    a1 = wave_sum(a1); a2 = wave_sum(a2);
    b1 = wave_sum(b1); b2 = wave_sum(b2);
    c1 = wave_sum(c1); c2 = wave_sum(c2);
    int w = threadIdx.x >> 6;
    if ((threadIdx.x & 63) == 0) {
        part[w][0] = a1; part[w][1] = a2; part[w][2] = b1;
        part[w][3] = b2; part[w][4] = c1; part[w][5] = c2;
    }
    __syncthreads();
    if (threadIdx.x < 6) {
        float s = part[0][threadIdx.x] + part[1][threadIdx.x] + part[2][threadIdx.x] + part[3][threadIdx.x];
        pbuf[blockIdx.x * 6 + threadIdx.x] = s;
    }
}

__global__ void enc_reduce_stage2(const float* __restrict__ pbuf, float* __restrict__ est) {
    int lane = threadIdx.x;
    float s[6] = {};
    for (int b = lane; b < ERB; b += 64)
#pragma unroll
        for (int j = 0; j < 6; ++j) s[j] += pbuf[b * 6 + j];
#pragma unroll
    for (int j = 0; j < 6; ++j) {
        float v = wave_sum(s[j]);
        if (lane == 0) est[j] = v;
    }
    __syncthreads();
    if (lane < 3) {
        float cnt = (float)NN * 128.f;
        float mean = est[2 * lane] / cnt;
        float var = est[2 * lane + 1] / cnt - mean * mean;
        var = fmaxf(var, 0.f);
        est[6 + 2 * lane] = mean;
        est[7 + 2 * lane] = 1.f / (sqrtf(var) + 1e-5f);
    }
}

__global__ __launch_bounds__(256) void enc_apply(
    float* __restrict__ h0, unsigned short* __restrict__ hb, const float* __restrict__ est,
    const float* __restrict__ lw0, const float* __restrict__ lb0,
    const float* __restrict__ lw1, const float* __restrict__ lb1,
    const float* __restrict__ lw2, const float* __restrict__ lb2)
{
    long gt = (long)blockIdx.x * 256 + threadIdx.x;
    if (gt >= (long)NN * FF) return;
    int f = (int)(gt % FF);
    int enc = f >> 7, j = f & 127;
    const float* lw = enc == 0 ? lw0 : (enc == 1 ? lw1 : lw2);
    const float* lb = enc == 0 ? lb0 : (enc == 1 ? lb1 : lb2);
    float mean = est[6 + 2 * enc], sc = est[7 + 2 * enc];
    float v = (h0[gt] - mean) * sc * lw[j] + lb[j];
    h0[gt] = v;
    hb[gt] = f2bf(v);
}

// ================= qkbuf via MFMA: [N,384] @ [384,48] from h directly =================
// qkbuf[n][r*16 + 0..7] = qi dots, [r*16 + 8..15] = kj dots
__global__ __launch_bounds__(256) void qk48_mfma(
    const unsigned short* __restrict__ hb,
    const unsigned short* __restrict__ wqkt,
    float* __restrict__ qkbuf)
{
    __shared__ __align__(16) unsigned short wlds[48 * 392];
    int t = threadIdx.x;
    for (int idx = t; idx < 48 * 192; idx += 256) {
        int row = idx / 192, dw = idx - row * 192;
        *((unsigned*)(wlds + row * 392) + dw) = ((const unsigned*)wqkt)[row * 192 + dw];
    }
    __syncthreads();
    int lane = t & 63, wid = t >> 6;
    int col = lane & 15, kq = lane >> 4;
    int tile = blockIdx.x * 4 + wid;
    const unsigned short* arow = hb + (size_t)(tile * 16 + col) * FF + kq * 8;
    f32x4 acc0 = {}, acc1 = {}, acc2 = {};
#pragma unroll
    for (int kt = 0; kt < 12; ++kt) {
        bf16x8 af = *(const bf16x8*)(arow + kt * 32);
        bf16x8 b0 = *(const bf16x8*)(wlds + (0 * 16 + col) * 392 + kt * 32 + kq * 8);
        bf16x8 b1 = *(const bf16x8*)(wlds + (1 * 16 + col) * 392 + kt * 32 + kq * 8);
        bf16x8 b2 = *(const bf16x8*)(wlds + (2 * 16 + col) * 392 + kt * 32 + kq * 8);
        acc0 = __builtin_amdgcn_mfma_f32_16x16x32_bf16(af, b0, acc0, 0, 0, 0);
        acc1 = __builtin_amdgcn_mfma_f32_16x16x32_bf16(af, b1, acc1, 0, 0, 0);
        acc2 = __builtin_amdgcn_mfma_f32_16x16x32_bf16(af, b2, acc2, 0, 0, 0);
    }
    int row0 = kq << 2;
#pragma unroll
    for (int j = 0; j < 4; ++j) {
        size_t node = (size_t)tile * 16 + row0 + j;
        qkbuf[node * 48 + 0 + col]  = acc0[j];
        qkbuf[node * 48 + 16 + col] = acc1[j];
        qkbuf[node * 48 + 32 + col] = acc2[j];
    }
}

// ================= fused softmax + weighted xt gather + elu + residual + graph stats =================
__global__ __launch_bounds__(256) void gather_fused(
    const int* __restrict__ rps, const int* __restrict__ deg, const int* __restrict__ elist,
    const float* __restrict__ qkbuf, const unsigned short* __restrict__ xt,
    const float* __restrict__ hin, const float* __restrict__ rb, const int* __restrict__ batch,
    float* __restrict__ gs1, float* __restrict__ gs2, float* __restrict__ ybuf)
{
    int node = blockIdx.x * 4 + (threadIdx.x >> 6);
    int lane = threadIdx.x & 63;
    int d = deg[node], rp = rps[node];
    int head = lane >> 3;
    float qd0 = qkbuf[(size_t)node * 48 + 0 + head];
    float qd1 = qkbuf[(size_t)node * 48 + 16 + head];
    float qd2 = qkbuf[(size_t)node * 48 + 32 + head];
    // pass A: online softmax stats across all in-edges (segment softmax spans relations)
    float m = -3.4e38f, s = 0.f;
    for (int e = 0; e < d; ++e) {
        int packed = elist[rp + e];
        int et = packed >> 16, src = packed & 0xFFFF;
        float qd = et == 0 ? qd0 : (et == 1 ? qd1 : qd2);
        float a = qd + qkbuf[(size_t)src * 48 + et * 16 + 8 + head];
        a = a >= 0.f ? a : NEG_SLOPE * a;
        float mn = fmaxf(m, a);
        s = s * __expf(m - mn) + __expf(a - mn);
        m = mn;
    }
    float inv = 1.f / (s + 1e-16f);
    // pass B: weighted gather of xt rows
    int f0 = lane * 6;
    float acc0 = 0.f, acc1 = 0.f, acc2 = 0.f, acc3 = 0.f, acc4 = 0.f, acc5 = 0.f;
    for (int e = 0; e < d; ++e) {
        int packed = elist[rp + e];
        int et = packed >> 16, src = packed & 0xFFFF;
        float qd = et == 0 ? qd0 : (et == 1 ? qd1 : qd2);
        float a = qd + qkbuf[(size_t)src * 48 + et * 16 + 8 + head];
        a = a >= 0.f ? a : NEG_SLOPE * a;
        float w = __expf(a - m) * inv;
        const unsigned* xr = (const unsigned*)(xt + ((size_t)et * NN + src) * FF) + lane * 3;
        unsigned u0 = xr[0], u1 = xr[1], u2 = xr[2];
        acc0 = fmaf(w, bflo(u0), acc0); acc1 = fmaf(w, bfhi(u0), acc1);
        acc2 = fmaf(w, bflo(u1), acc2); acc3 = fmaf(w, bfhi(u1), acc3);
        acc4 = fmaf(w, bflo(u2), acc4); acc5 = fmaf(w, bfhi(u2), acc5);
    }
    // fused post: y = hin + elu(msg + rb), per-graph stats
    float s1 = 0.f, s2 = 0.f;
    float av[6] = {acc0, acc1, acc2, acc3, acc4, acc5};
#pragma unroll
    for (int i = 0; i < 6; ++i) {
        int f = f0 + i;
        float mv = av[i] + rb[f];
        float e = mv > 0.f ? mv : (__expf(mv) - 1.f);
        float y = hin[(size_t)node * FF + f] + e;
        ybuf[(size_t)node * FF + f] = y;
        s1 += y; s2 += y * y;
    }
    s1 = wave_sum(s1);
    s2 = wave_sum(s2);
    if (lane == 0) {
        int g = batch[node];
        atomicAdd(&gs1[g], s1);
        atomicAdd(&gs2[g], s2);
    }
}

__global__ void graph_finalize(
    const float* __restrict__ gcnt, const float* __restrict__ gs1, const float* __restrict__ gs2,
    float* __restrict__ gmean, float* __restrict__ grstd)
{
    int g = blockIdx.x * 64 + threadIdx.x;
    if (g >= GG) return;
    float cnt = fmaxf(gcnt[g], 1.f) * (float)FF;
    float mean = gs1[g] / cnt;
    float var = gs2[g] / cnt - mean * mean;
    var = fmaxf(var, 0.f);
    gmean[g] = mean;
    grstd[g] = 1.f / sqrtf(var + 1e-5f);
}

__global__ __launch_bounds__(256) void ln_apply(
    const float* __restrict__ y, const int* __restrict__ batch,
    const float* __restrict__ gmean, const float* __restrict__ grstd,
    const float* __restrict__ w, const float* __restrict__ b,
    float* __restrict__ hout, unsigned short* __restrict__ hb)
{
    long gt = (long)blockIdx.x * 256 + threadIdx.x;
    int n = (int)(gt >> 6);
    if (n >= NN) return;
    int lane = (int)(gt & 63);
    int f0 = lane * 6;
    int g = batch[n];
    float mean = gmean[g], rs = grstd[g];
#pragma unroll
    for (int i = 0; i < 6; ++i) {
        int f = f0 + i;
        float v = (y[(size_t)n * FF + f] - mean) * rs * w[f] + b[f];
        hout[(size_t)n * FF + f] = v;
        hb[(size_t)n * FF + f] = f2bf(v);
    }
}

// ================= host-side layer driver =================
static void rgat_layer(hipStream_t stream,
    const float* hin, const unsigned short* hbIn,
    const float* rw, const float* rq, const float* rk, const float* rb,
    const float* lnw, const float* lnb,
    const int* rps, const int* deg, const int* elist, const int* batch,
    unsigned short* wt, unsigned short* xt,
    float* wqf, float* wkf, unsigned short* wqkt, float* qkbuf,
    float* gs1, float* gs2, const float* gcnt, float* gmean, float* grstd,
    float* ybuf, float* hout, unsigned short* hbOut)
{
    hipMemsetAsync(gs1, 0, GG * 4, stream);
    hipMemsetAsync(gs2, 0, GG * 4, stream);
    // weight prep
    int tt = 3 * FF * FF;
    transpose_bf<<<(tt + 255) / 256, 256, 0, stream>>>(rw, wt, FF, FF, tt);
    gemm_k<0><<<dim3(1, 6, 3), 256, 0, stream>>>(rw, FF, rq, 8, nullptr, wqf, 8, 8, 0, 3072, (size_t)FF * FF);
    gemm_k<0><<<dim3(1, 6, 3), 256, 0, stream>>>(rw, FF, rk, 8, nullptr, wkf, 8, 8, 0, 3072, (size_t)FF * FF);
    qkw_pack<<<72, 256, 0, stream>>>(wqf, wkf, wqkt);
    // xt[r] = h @ W_r  (bf16)
    gemm_mfma<0, true, true><<<dim3(3, 384, 3), 256, 0, stream>>>(
        hbIn, FF, wt, nullptr, xt, FF, (size_t)FF * FF, (size_t)NN * FF);
    // qkbuf = h @ Wqk  [N,48]
    qk48_mfma<<<NN / 64, 256, 0, stream>>>(hbIn, wqkt, qkbuf);
    // fused softmax + gather + post
    gather_fused<<<NN / 4, 256, 0, stream>>>(rps, deg, elist, qkbuf, xt, hin, rb, batch, gs1, gs2, ybuf);
    graph_finalize<<<GG / 64, 64, 0, stream>>>(gcnt, gs1, gs2, gmean, grstd);
    ln_apply<<<NN / 4, 256, 0, stream>>>(ybuf, batch, gmean, grstd, lnw, lnb, hout, hbOut);
}

extern "C" void kernel_launch(void* const* d_in, const int* in_sizes, int n_in,
                              void* d_out, int out_size, void* d_ws, size_t ws_size,
                              hipStream_t stream)
{
    const float* x_visual = (const float*)d_in[0];
    const float* x_geom   = (const float*)d_in[1];
    const float* x_prior  = (const float*)d_in[2];
    const float* vis_w  = (const float*)d_in[3];
    const float* vis_b  = (const float*)d_in[4];
    const float* vis_lw = (const float*)d_in[5];
    const float* vis_lb = (const float*)d_in[6];
    const float* geom_w  = (const float*)d_in[7];
    const float* geom_b  = (const float*)d_in[8];
    const float* geom_lw = (const float*)d_in[9];
    const float* geom_lb = (const float*)d_in[10];
    const float* prior_w  = (const float*)d_in[11];
    const float* prior_b  = (const float*)d_in[12];
    const float* prior_lw = (const float*)d_in[13];
    const float* prior_lb = (const float*)d_in[14];
    const float* r1_w = (const float*)d_in[15];
    const float* r1_q = (const float*)d_in[16];
    const float* r1_k = (const float*)d_in[17];
    const float* r1_b = (const float*)d_in[18];
    const float* n1_w = (const float*)d_in[19];
    const float* n1_b = (const float*)d_in[20];
    const float* r2_w = (const float*)d_in[21];
    const float* r2_q = (const float*)d_in[22];
    const float* r2_k = (const float*)d_in[23];
    const float* r2_b = (const float*)d_in[24];
    const float* n2_w = (const float*)d_in[25];
    const float* n2_b = (const float*)d_in[26];
    const float* c_w1 = (const float*)d_in[27];
    const float* c_b1 = (const float*)d_in[28];
    const float* c_w2 = (const float*)d_in[29];
    const float* c_b2 = (const float*)d_in[30];
    const int* ei_o  = (const int*)d_in[31];
    const int* ei_a  = (const int*)d_in[32];
    const int* ei_s  = (const int*)d_in[33];
    const int* batch = (const int*)d_in[34];
    float* out = (float*)d_out;

    char* p = (char*)d_ws;
    auto alloc = [&](size_t bytes) { char* r = p; p += (bytes + 255) & ~(size_t)255; return r; };
    float* h0 = (float*)alloc((size_t)NN * FF * 4);
    float* h1 = (float*)alloc((size_t)NN * FF * 4);
    float* ybuf = (float*)alloc((size_t)NN * FF * 4);
    unsigned short* xt = (unsigned short*)alloc((size_t)3 * NN * FF * 2);
    unsigned short* hb = (unsigned short*)alloc((size_t)NN * FF * 2);
    unsigned short* wt = (unsigned short*)alloc((size_t)3 * FF * FF * 2);
    float* qkbuf = (float*)alloc((size_t)NN * 48 * 4);
    float* wqf = (float*)alloc((size_t)3 * FF * 8 * 4);
    float* wkf = (float*)alloc((size_t)3 * FF * 8 * 4);
    unsigned short* wqkt = (unsigned short*)alloc((size_t)48 * FF * 2);
    float* t128 = (float*)alloc((size_t)NN * 128 * 4);
    int* deg = (int*)alloc(NN * 4);
    int* rps = (int*)alloc(NN * 4);
    int* fill = (int*)alloc(NN * 4);
    int* elist = (int*)alloc(ETOT * 4);
    int* counter = (int*)alloc(256);
    float* gs1 = (float*)alloc(GG * 4);
    float* gs2 = (float*)alloc(GG * 4);
    float* gcnt = (float*)alloc(GG * 4);
    float* gmean = (float*)alloc(GG * 4);
    float* grstd = (float*)alloc(GG * 4);
    float* est = (float*)alloc(64);
    float* pbuf = (float*)alloc(ERB * 6 * 4);
    float* h2 = h0;  // reuse

    // ---- CSR build (once; shared by both layers) ----
    hipMemsetAsync(deg, 0, NN * 4, stream);
    hipMemsetAsync(fill, 0, NN * 4, stream);
    hipMemsetAsync(counter, 0, 4, stream);
    csr_count<<<ETOT / 256, 256, 0, stream>>>(ei_o, ei_a, ei_s, deg);
    csr_alloc<<<NN / 256, 256, 0, stream>>>(deg, counter, rps);
    csr_fill<<<ETOT / 256, 256, 0, stream>>>(ei_o, ei_a, ei_s, rps, fill, elist);

    // ---- per-graph node counts ----
    hipMemsetAsync(gcnt, 0, GG * 4, stream);
    count_nodes<<<NN / 256, 256, 0, stream>>>(batch, gcnt);

    // ---- encoders ----
    transpose_bf<<<(1024 * 128 + 255) / 256, 256, 0, stream>>>(vis_w, wt, 1024, 128, 1024 * 128);
    gemm_mfma<1, false, false><<<dim3(1, 384, 1), 256, 0, stream>>>(
        x_visual, 1024, wt, vis_b, h0, FF, 0, 0);
    gemm_k<1><<<dim3(2, 768, 1), 256, 0, stream>>>(x_geom, 6, geom_w, 128, geom_b, h0 + 128, FF, 128, 0, 0, 0);
    gemm_k<1><<<dim3(2, 768, 1), 256, 0, stream>>>(x_prior, 50, prior_w, 128, prior_b, h0 + 256, FF, 128, 0, 0, 0);
    enc_reduce_stage1<<<ERB, 256, 0, stream>>>(h0, pbuf);
    enc_reduce_stage2<<<1, 64, 0, stream>>>(pbuf, est);
    enc_apply<<<(int)((size_t)NN * FF / 256), 256, 0, stream>>>(
        h0, hb, est, vis_lw, vis_lb, geom_lw, geom_lb, prior_lw, prior_lb);

    // ---- RGAT layers ----
    rgat_layer(stream, h0, hb, r1_w, r1_q, r1_k, r1_b, n1_w, n1_b,
               rps, deg, elist, batch, wt, xt, wqf, wkf, wqkt, qkbuf,
               gs1, gs2, gcnt, gmean, grstd, ybuf, h1, hb);
    rgat_layer(stream, h1, hb, r2_w, r2_q, r2_k, r2_b, n2_w, n2_b,
               rps, deg, elist, batch, wt, xt, wqf, wkf, wqkt, qkbuf,
               gs1, gs2, gcnt, gmean, grstd, ybuf, h2, hb);

    // ---- classifier ----
    transpose_bf<<<(FF * 128 + 255) / 256, 256, 0, stream>>>(c_w1, wt, FF, 128, FF * 128);
    gemm_mfma<1, true, false><<<dim3(1, 384, 1), 256, 0, stream>>>(
        hb, FF, wt, c_b1, t128, 128, 0, 0);
    gemm_k<0><<<dim3(1, 768, 1), 256, 0, stream>>>(t128, 128, c_w2, 49, c_b2, out, 49, 49, 0, 0, 0);
}

// Round 8
// 781.574 us; speedup vs baseline: 1.2435x; 1.2435x over previous
//
#include <hip/hip_runtime.h>
#include <hip/hip_bf16.h>

#define NN 49152
#define GG 1024
#define EE 65536
#define ETOT 196608
#define FF 384
#define NEG_SLOPE 0.2f

typedef __attribute__((ext_vector_type(8))) short bf16x8;
typedef __attribute__((ext_vector_type(4))) float f32x4;

__device__ __forceinline__ float wave_sum(float v) {
#pragma unroll
    for (int m = 32; m; m >>= 1) v += __shfl_xor(v, m);
    return v;
}
__device__ __forceinline__ unsigned short f2bf(float f) {
    __hip_bfloat16 b = __float2bfloat16(f);
    return *reinterpret_cast<unsigned short*>(&b);
}
__device__ __forceinline__ float bflo(unsigned u) { return __uint_as_float(u << 16); }
__device__ __forceinline__ float bfhi(unsigned u) { return __uint_as_float(u & 0xffff0000u); }
__device__ __forceinline__ unsigned pk2(float lo, float hi) {
    return ((unsigned)f2bf(hi) << 16) | (unsigned)f2bf(lo);
}

__device__ __forceinline__ void gload_lds16(const void* g, void* l) {
    __builtin_amdgcn_global_load_lds(
        (const __attribute__((address_space(1))) unsigned int*)g,
        (__attribute__((address_space(3))) unsigned int*)l, 16, 0, 0);
}

// ================= MFMA bf16 GEMM: C = act(A @ Bt^T + bias) =================
// Grid: x = M-tiles (128), y = N-tiles (128), z = batch. Blocks sharing an
// A-tile are gridDim.x (=384 ≡ 0 mod 8) apart -> same XCD -> A L2-reuse.
// Physical LDS convention: position (row, c) holds logical chunk c ^ ((row>>1)&3).
__device__ __forceinline__ int swz(int row, int c16) {
    return row * 64 + ((c16 ^ ((row >> 1) & 3)) << 4);
}

template <int ACT, bool ABF, bool OBF>
__global__ __launch_bounds__(256) void gemm_mfma(
    const void* __restrict__ Ag, int K,
    const unsigned short* __restrict__ Btg,
    const float* __restrict__ bias,
    void* __restrict__ Cg, int ldc,
    size_t bzs, size_t czs)
{
    __shared__ __align__(16) char As[8192];
    __shared__ __align__(16) char Bs[8192];
    const unsigned short* Bt = Btg + (size_t)blockIdx.z * bzs;
    int t = threadIdx.x;
    int bm = blockIdx.x << 7, bn = blockIdx.y << 7;
    int lane = t & 63, wid = t >> 6, wr = wid >> 1, wc = wid & 1;
    f32x4 acc[4][4] = {};
    int ktn = K >> 5;
    for (int kt = 0; kt < ktn; ++kt) {
        int k0 = kt << 5;
#pragma unroll
        for (int ii = 0; ii < 2; ++ii) {
            int id = t + (ii << 8);
            int row = id >> 2, c = id & 3;
            int csrc = c ^ ((row >> 1) & 3);  // pre-swizzled source chunk
            size_t ldsoff = (size_t)((wid << 10) + (ii << 12));  // wave-uniform offset
            if (ABF) {
                const unsigned short* srcA = (const unsigned short*)Ag + (size_t)(bm + row) * K + k0 + csrc * 8;
                gload_lds16(srcA, As + ldsoff);
            } else {
                const float* srcA = (const float*)Ag + (size_t)(bm + row) * K + k0 + c * 8;
                float4 a0 = *(const float4*)srcA;
                float4 a1 = *(const float4*)(srcA + 4);
                union { unsigned short u[8]; int4 v; } P;
                P.u[0] = f2bf(a0.x); P.u[1] = f2bf(a0.y); P.u[2] = f2bf(a0.z); P.u[3] = f2bf(a0.w);
                P.u[4] = f2bf(a1.x); P.u[5] = f2bf(a1.y); P.u[6] = f2bf(a1.z); P.u[7] = f2bf(a1.w);
                *(int4*)(As + swz(row, c)) = P.v;
            }
            const unsigned short* srcB = Bt + (size_t)(bn + row) * K + k0 + csrc * 8;
            gload_lds16(srcB, Bs + ldsoff);
        }
        __syncthreads();
        int c16 = lane >> 4;
        bf16x8 af[4], bfr[4];
#pragma unroll
        for (int m = 0; m < 4; ++m)
            af[m] = *(const bf16x8*)(As + swz((wr << 6) + (m << 4) + (lane & 15), c16));
#pragma unroll
        for (int n = 0; n < 4; ++n)
            bfr[n] = *(const bf16x8*)(Bs + swz((wc << 6) + (n << 4) + (lane & 15), c16));
#pragma unroll
        for (int m = 0; m < 4; ++m)
#pragma unroll
            for (int n = 0; n < 4; ++n)
                acc[m][n] = __builtin_amdgcn_mfma_f32_16x16x32_bf16(af[m], bfr[n], acc[m][n], 0, 0, 0);
        __syncthreads();
    }
#pragma unroll
    for (int m = 0; m < 4; ++m) {
#pragma unroll
        for (int n = 0; n < 4; ++n) {
            int row0 = bm + (wr << 6) + (m << 4) + ((lane >> 4) << 2);
            int col = bn + (wc << 6) + (n << 4) + (lane & 15);
            float bv = bias ? bias[col] : 0.f;
#pragma unroll
            for (int j = 0; j < 4; ++j) {
                float v = acc[m][n][j] + bv;
                if (ACT == 1) v = fmaxf(v, 0.f);
                if (OBF) {
                    unsigned short* C = (unsigned short*)Cg + (size_t)blockIdx.z * czs;
                    C[(size_t)(row0 + j) * ldc + col] = f2bf(v);
                } else {
                    float* C = (float*)Cg + (size_t)blockIdx.z * czs;
                    C[(size_t)(row0 + j) * ldc + col] = v;
                }
            }
        }
    }
}

// ================= f32 fallback GEMM (small K / small N) =================
template <int ACT>
__global__ __launch_bounds__(256) void gemm_k(
    const float* __restrict__ A, int K,
    const float* __restrict__ Wg, int Jw,
    const float* __restrict__ bias,
    float* __restrict__ Cg, int ldc, int jmax)
{
    __shared__ float Ash[16][64];
    __shared__ float Bsh[16][68];
    const float* W = Wg;
    float* C = Cg;
    int tid = threadIdx.x;
    int bj = blockIdx.x << 6;
    int bm = blockIdx.y << 6;
    int tx = tid & 15, ty = tid >> 4;
    float acc[4][4] = {};
    int ktn = (K + 15) >> 4;
    int ar = tid >> 2;
    int aks = (tid & 3) << 2;
    int wk = tid >> 4;
    int wjs = (tid & 15) << 2;
    for (int kt = 0; kt < ktn; ++kt) {
        int k0 = kt << 4;
        const float* Ap = A + (size_t)(bm + ar) * K + k0 + aks;
#pragma unroll
        for (int i = 0; i < 4; ++i) {
            int k = k0 + aks + i;
            Ash[aks + i][ar] = (k < K) ? Ap[i] : 0.f;
        }
        const float* Wp = W + (size_t)(k0 + wk) * Jw + bj + wjs;
        bool kok = (k0 + wk) < K;
#pragma unroll
        for (int i = 0; i < 4; ++i) {
            int j = bj + wjs + i;
            Bsh[wk][wjs + i] = (kok && j < jmax) ? Wp[i] : 0.f;
        }
        __syncthreads();
#pragma unroll
        for (int kk = 0; kk < 16; ++kk) {
            const float4 av = *reinterpret_cast<const float4*>(&Ash[kk][ty << 2]);
            const float4 bv = *reinterpret_cast<const float4*>(&Bsh[kk][tx << 2]);
            float aa[4] = {av.x, av.y, av.z, av.w};
            float bb[4] = {bv.x, bv.y, bv.z, bv.w};
#pragma unroll
            for (int i = 0; i < 4; ++i)
#pragma unroll
                for (int j = 0; j < 4; ++j)
                    acc[i][j] = fmaf(aa[i], bb[j], acc[i][j]);
        }
        __syncthreads();
    }
#pragma unroll
    for (int i = 0; i < 4; ++i) {
        int row = bm + (ty << 2) + i;
#pragma unroll
        for (int j = 0; j < 4; ++j) {
            int col = bj + (tx << 2) + j;
            if (col < jmax) {
                float v = acc[i][j];
                if (bias) v += bias[col];
                if (ACT == 1) v = fmaxf(v, 0.f);
                C[(size_t)row * ldc + col] = v;
            }
        }
    }
}

// ================= weight transpose + bf16 convert: Wt[z][n][k] = W[z][k][n] =================
__global__ void transpose_bf(const float* __restrict__ W, unsigned short* __restrict__ Wt,
                             int K, int N, int total) {
    int i = blockIdx.x * 256 + threadIdx.x;
    if (i >= total) return;
    int kn = K * N;
    int z = i / kn, rem = i - z * kn;
    int k = rem / N, n = rem - k * N;
    Wt[(size_t)z * kn + (size_t)n * K + k] = f2bf(W[i]);
}

// ================= wqkt[r*16 + qk*8 + h][f] = sum_c rw[r][f][c] * (qk?k:q)[c][h] =================
// grid (3, 6): (relation, 64-row f-tile); 256 threads
__global__ __launch_bounds__(256) void wqk_prep(
    const float* __restrict__ rw, const float* __restrict__ q, const float* __restrict__ k,
    unsigned short* __restrict__ wqkt)
{
    __shared__ float qsT[16 * 384];  // [j][c]
    int t = threadIdx.x;
    int r = blockIdx.x, ftile = blockIdx.y;
    for (int idx = t; idx < 384 * 16; idx += 256) {
        int c = idx >> 4, j = idx & 15;
        qsT[j * 384 + c] = (j < 8) ? q[c * 8 + j] : k[c * 8 + j - 8];
    }
    __syncthreads();
    int j = t & 15, fi = t >> 4;
    const float4* q4 = (const float4*)(qsT + j * 384);
#pragma unroll
    for (int rr = 0; rr < 4; ++rr) {
        int f = ftile * 64 + fi * 4 + rr;
        const float4* a4 = (const float4*)(rw + (size_t)r * FF * FF + (size_t)f * FF);
        float dot = 0.f;
        for (int c4 = 0; c4 < 96; ++c4) {
            float4 a = a4[c4], b = q4[c4];
            dot += a.x * b.x + a.y * b.y + a.z * b.z + a.w * b.w;
        }
        wqkt[(size_t)(r * 16 + j) * FF + f] = f2bf(dot);
    }
}

// ================= CSR build =================
__global__ void csr_count(const int* __restrict__ eo, const int* __restrict__ ea,
                          const int* __restrict__ es, int* __restrict__ deg) {
    int e = blockIdx.x * 256 + threadIdx.x;
    if (e >= ETOT) return;
    int et = e >> 16, le = e & 65535;
    const int* ei = et == 0 ? eo : (et == 1 ? ea : es);
    atomicAdd(&deg[ei[EE + le]], 1);
}
__global__ void csr_alloc(const int* __restrict__ deg, int* __restrict__ counter,
                          int* __restrict__ rps) {
    int n = blockIdx.x * 256 + threadIdx.x;
    int lane = threadIdx.x & 63;
    int d = (n < NN) ? deg[n] : 0;
    int x = d;
#pragma unroll
    for (int off = 1; off < 64; off <<= 1) {
        int y = __shfl_up(x, off);
        if (lane >= off) x += y;
    }
    int total = __shfl(x, 63);
    int base = 0;
    if (lane == 63) base = atomicAdd(counter, total);
    base = __shfl(base, 63);
    if (n < NN) rps[n] = base + x - d;
}
__global__ void csr_fill(const int* __restrict__ eo, const int* __restrict__ ea,
                         const int* __restrict__ es, const int* __restrict__ rps,
                         int* __restrict__ fill, int* __restrict__ elist) {
    int e = blockIdx.x * 256 + threadIdx.x;
    if (e >= ETOT) return;
    int et = e >> 16, le = e & 65535;
    const int* ei = et == 0 ? eo : (et == 1 ? ea : es);
    int src = ei[le], dst = ei[EE + le];
    int pos = rps[dst] + atomicAdd(&fill[dst], 1);
    elist[pos] = (et << 16) | src;
}

// ================= misc =================
__global__ void count_nodes(const int* __restrict__ batch, float* __restrict__ gcnt) {
    int n = blockIdx.x * 256 + threadIdx.x;
    if (n < NN) atomicAdd(&gcnt[batch[n]], 1.f);
}

// ================= encoder stats: two-stage, no atomics =================
#define ERB 512
__global__ __launch_bounds__(256) void enc_reduce_stage1(const float* __restrict__ h0, float* __restrict__ pbuf) {
    __shared__ float part[4][6];
    float a1 = 0.f, a2 = 0.f, b1 = 0.f, b2 = 0.f, c1 = 0.f, c2 = 0.f;
    const float4* h4 = (const float4*)h0;
    int total4 = NN * FF / 4;
    for (int i = blockIdx.x * 256 + threadIdx.x; i < total4; i += ERB * 256) {
        float4 v = h4[i];
        float s1 = v.x + v.y + v.z + v.w;
        float s2 = v.x * v.x + v.y * v.y + v.z * v.z + v.w * v.w;
        int enc = (i % 96) >> 5;
        if (enc == 0)      { a1 += s1; a2 += s2; }
        else if (enc == 1) { b1 += s1; b2 += s2; }
        else               { c1 += s1; c2 += s2; }
    }
    a1 = wave_sum(a1); a2 = wave_sum(a2);
    b1 = wave_sum(b1); b2 = wave_sum(b2);
    c1 = wave_sum(c1); c2 = wave_sum(c2);
    int w = threadIdx.x >> 6;
    if ((threadIdx.x & 63) == 0) {
        part[w][0] = a1; part[w][1] = a2; part[w][2] = b1;
        part[w][3] = b2; part[w][4] = c1; part[w][5] = c2;
    }
    __syncthreads();
    if (threadIdx.x < 6) {
        float s = part[0][threadIdx.x] + part[1][threadIdx.x] + part[2][threadIdx.x] + part[3][threadIdx.x];
        pbuf[blockIdx.x * 6 + threadIdx.x] = s;
    }
}

__global__ void enc_reduce_stage2(const float* __restrict__ pbuf, float* __restrict__ est) {
    int lane = threadIdx.x;
    float s[6] = {};
    for (int b = lane; b < ERB; b += 64)
#pragma unroll
        for (int j = 0; j < 6; ++j) s[j] += pbuf[b * 6 + j];
#pragma unroll
    for (int j = 0; j < 6; ++j) {
        float v = wave_sum(s[j]);
        if (lane == 0) est[j] = v;
    }
    __syncthreads();
    if (lane < 3) {
        float cnt = (float)NN * 128.f;
        float mean = est[2 * lane] / cnt;
        float var = est[2 * lane + 1] / cnt - mean * mean;
        var = fmaxf(var, 0.f);
        est[6 + 2 * lane] = mean;
        est[7 + 2 * lane] = 1.f / (sqrtf(var) + 1e-5f);
    }
}

__global__ __launch_bounds__(256) void enc_apply(
    const float* __restrict__ h0, unsigned short* __restrict__ hb, const float* __restrict__ est,
    const float* __restrict__ lw0, const float* __restrict__ lb0,
    const float* __restrict__ lw1, const float* __restrict__ lb1,
    const float* __restrict__ lw2, const float* __restrict__ lb2)
{
    long gt = (long)blockIdx.x * 256 + threadIdx.x;
    if (gt >= (long)NN * FF) return;
    int f = (int)(gt % FF);
    int enc = f >> 7, j = f & 127;
    const float* lw = enc == 0 ? lw0 : (enc == 1 ? lw1 : lw2);
    const float* lb = enc == 0 ? lb0 : (enc == 1 ? lb1 : lb2);
    float mean = est[6 + 2 * enc], sc = est[7 + 2 * enc];
    float v = (h0[gt] - mean) * sc * lw[j] + lb[j];
    hb[gt] = f2bf(v);
}

// ================= qkbuf via MFMA: [N,384] @ [384,48] from h directly =================
__global__ __launch_bounds__(256) void qk48_mfma(
    const unsigned short* __restrict__ hb,
    const unsigned short* __restrict__ wqkt,
    float* __restrict__ qkbuf)
{
    __shared__ __align__(16) unsigned short wlds[48 * 392];
    int t = threadIdx.x;
    for (int idx = t; idx < 48 * 192; idx += 256) {
        int row = idx / 192, dw = idx - row * 192;
        *((unsigned*)(wlds + row * 392) + dw) = ((const unsigned*)wqkt)[row * 192 + dw];
    }
    __syncthreads();
    int lane = t & 63, wid = t >> 6;
    int col = lane & 15, kq = lane >> 4;
    int tile = blockIdx.x * 4 + wid;
    const unsigned short* arow = hb + (size_t)(tile * 16 + col) * FF + kq * 8;
    f32x4 acc0 = {}, acc1 = {}, acc2 = {};
#pragma unroll
    for (int kt = 0; kt < 12; ++kt) {
        bf16x8 af = *(const bf16x8*)(arow + kt * 32);
        bf16x8 b0 = *(const bf16x8*)(wlds + (0 * 16 + col) * 392 + kt * 32 + kq * 8);
        bf16x8 b1 = *(const bf16x8*)(wlds + (1 * 16 + col) * 392 + kt * 32 + kq * 8);
        bf16x8 b2 = *(const bf16x8*)(wlds + (2 * 16 + col) * 392 + kt * 32 + kq * 8);
        acc0 = __builtin_amdgcn_mfma_f32_16x16x32_bf16(af, b0, acc0, 0, 0, 0);
        acc1 = __builtin_amdgcn_mfma_f32_16x16x32_bf16(af, b1, acc1, 0, 0, 0);
        acc2 = __builtin_amdgcn_mfma_f32_16x16x32_bf16(af, b2, acc2, 0, 0, 0);
    }
    int row0 = kq << 2;
#pragma unroll
    for (int j = 0; j < 4; ++j) {
        size_t node = (size_t)tile * 16 + row0 + j;
        qkbuf[node * 48 + 0 + col]  = acc0[j];
        qkbuf[node * 48 + 16 + col] = acc1[j];
        qkbuf[node * 48 + 32 + col] = acc2[j];
    }
}

// ================= single-pass online softmax + weighted xt gather + elu + residual + stats =================
__global__ __launch_bounds__(256) void gather_fused(
    const int* __restrict__ rps, const int* __restrict__ deg, const int* __restrict__ elist,
    const float* __restrict__ qkbuf, const unsigned short* __restrict__ xt,
    const unsigned short* __restrict__ hbin, const float* __restrict__ rb, const int* __restrict__ batch,
    float* __restrict__ gs1, float* __restrict__ gs2, unsigned short* __restrict__ ybuf)
{
    int node = blockIdx.x * 4 + (threadIdx.x >> 6);
    int lane = threadIdx.x & 63;
    int d = deg[node], rp = rps[node];
    int head = lane >> 3;
    float qd0 = qkbuf[(size_t)node * 48 + 0 + head];
    float qd1 = qkbuf[(size_t)node * 48 + 16 + head];
    float qd2 = qkbuf[(size_t)node * 48 + 32 + head];
    float m = -3.4e38f, s = 0.f;
    float acc0 = 0.f, acc1 = 0.f, acc2 = 0.f, acc3 = 0.f, acc4 = 0.f, acc5 = 0.f;
    for (int e = 0; e < d; ++e) {
        int packed = elist[rp + e];
        int et = packed >> 16, src = packed & 0xFFFF;
        // issue feature gather first (independent of alpha math)
        const unsigned* xr = (const unsigned*)(xt + ((size_t)et * NN + src) * FF) + lane * 3;
        unsigned u0 = xr[0], u1 = xr[1], u2 = xr[2];
        float qd = et == 0 ? qd0 : (et == 1 ? qd1 : qd2);
        float a = qd + qkbuf[(size_t)src * 48 + et * 16 + 8 + head];
        a = a >= 0.f ? a : NEG_SLOPE * a;
        if (a > m) {
            float c = __expf(m - a);  // first iter: exp(-inf) = 0
            s = s * c + 1.f;
            acc0 = fmaf(acc0, c, bflo(u0)); acc1 = fmaf(acc1, c, bfhi(u0));
            acc2 = fmaf(acc2, c, bflo(u1)); acc3 = fmaf(acc3, c, bfhi(u1));
            acc4 = fmaf(acc4, c, bflo(u2)); acc5 = fmaf(acc5, c, bfhi(u2));
            m = a;
        } else {
            float pw = __expf(a - m);
            s += pw;
            acc0 = fmaf(pw, bflo(u0), acc0); acc1 = fmaf(pw, bfhi(u0), acc1);
            acc2 = fmaf(pw, bflo(u1), acc2); acc3 = fmaf(pw, bfhi(u1), acc3);
            acc4 = fmaf(pw, bflo(u2), acc4); acc5 = fmaf(pw, bfhi(u2), acc5);
        }
    }
    float inv = 1.f / (s + 1e-16f);
    // fused post: y = hin + elu(msg + rb), per-graph stats, bf16 store
    const unsigned* hr = (const unsigned*)(hbin + (size_t)node * FF) + lane * 3;
    unsigned h0u = hr[0], h1u = hr[1], h2u = hr[2];
    float hv[6] = {bflo(h0u), bfhi(h0u), bflo(h1u), bfhi(h1u), bflo(h2u), bfhi(h2u)};
    float av[6] = {acc0, acc1, acc2, acc3, acc4, acc5};
    int f0 = lane * 6;
    float s1 = 0.f, s2 = 0.f;
    float yv[6];
#pragma unroll
    for (int i = 0; i < 6; ++i) {
        float mv = av[i] * inv + rb[f0 + i];
        float e = mv > 0.f ? mv : (__expf(mv) - 1.f);
        float y = hv[i] + e;
        yv[i] = y;
        s1 += y; s2 += y * y;
    }
    unsigned* yrow = (unsigned*)(ybuf + (size_t)node * FF) + lane * 3;
    yrow[0] = pk2(yv[0], yv[1]);
    yrow[1] = pk2(yv[2], yv[3]);
    yrow[2] = pk2(yv[4], yv[5]);
    s1 = wave_sum(s1);
    s2 = wave_sum(s2);
    if (lane == 0) {
        int g = batch[node];
        atomicAdd(&gs1[g], s1);
        atomicAdd(&gs2[g], s2);
    }
}

__global__ void graph_finalize(
    const float* __restrict__ gcnt, const float* __restrict__ gs1, const float* __restrict__ gs2,
    float* __restrict__ gmean, float* __restrict__ grstd)
{
    int g = blockIdx.x * 64 + threadIdx.x;
    if (g >= GG) return;
    float cnt = fmaxf(gcnt[g], 1.f) * (float)FF;
    float mean = gs1[g] / cnt;
    float var = gs2[g] / cnt - mean * mean;
    var = fmaxf(var, 0.f);
    gmean[g] = mean;
    grstd[g] = 1.f / sqrtf(var + 1e-5f);
}

__global__ __launch_bounds__(256) void ln_apply(
    const unsigned short* __restrict__ y, const int* __restrict__ batch,
    const float* __restrict__ gmean, const float* __restrict__ grstd,
    const float* __restrict__ w, const float* __restrict__ b,
    unsigned short* __restrict__ hbOut)
{
    long gt = (long)blockIdx.x * 256 + threadIdx.x;
    int n = (int)(gt >> 6);
    if (n >= NN) return;
    int lane = (int)(gt & 63);
    int f0 = lane * 6;
    int g = batch[n];
    float mean = gmean[g], rs = grstd[g];
    const unsigned* yr = (const unsigned*)(y + (size_t)n * FF) + lane * 3;
    unsigned u0 = yr[0], u1 = yr[1], u2 = yr[2];
    float yv[6] = {bflo(u0), bfhi(u0), bflo(u1), bfhi(u1), bflo(u2), bfhi(u2)};
    float ov[6];
#pragma unroll
    for (int i = 0; i < 6; ++i)
        ov[i] = (yv[i] - mean) * rs * w[f0 + i] + b[f0 + i];
    unsigned* orow = (unsigned*)(hbOut + (size_t)n * FF) + lane * 3;
    orow[0] = pk2(ov[0], ov[1]);
    orow[1] = pk2(ov[2], ov[3]);
    orow[2] = pk2(ov[4], ov[5]);
}

// ================= host-side layer driver =================
static void rgat_layer(hipStream_t stream,
    const unsigned short* hbIn,
    const float* rw, const float* rq, const float* rk, const float* rb,
    const float* lnw, const float* lnb,
    const int* rps, const int* deg, const int* elist, const int* batch,
    unsigned short* wt, unsigned short* xt, unsigned short* wqkt, float* qkbuf,
    float* gs1, float* gs2, const float* gcnt, float* gmean, float* grstd,
    unsigned short* ybuf, unsigned short* hbOut)
{
    hipMemsetAsync(gs1, 0, GG * 4, stream);
    hipMemsetAsync(gs2, 0, GG * 4, stream);
    int tt = 3 * FF * FF;
    transpose_bf<<<(tt + 255) / 256, 256, 0, stream>>>(rw, wt, FF, FF, tt);
    wqk_prep<<<dim3(3, 6), 256, 0, stream>>>(rw, rq, rk, wqkt);
    // xt[r] = h @ W_r  (bf16)  — grid: (M-tiles, N-tiles, relation)
    gemm_mfma<0, true, true><<<dim3(384, 3, 3), 256, 0, stream>>>(
        hbIn, FF, wt, nullptr, xt, FF, (size_t)FF * FF, (size_t)NN * FF);
    // qkbuf = h @ Wqk  [N,48]
    qk48_mfma<<<NN / 64, 256, 0, stream>>>(hbIn, wqkt, qkbuf);
    // single-pass fused softmax + gather + post
    gather_fused<<<NN / 4, 256, 0, stream>>>(rps, deg, elist, qkbuf, xt, hbIn, rb, batch, gs1, gs2, ybuf);
    graph_finalize<<<GG / 64, 64, 0, stream>>>(gcnt, gs1, gs2, gmean, grstd);
    ln_apply<<<NN / 4, 256, 0, stream>>>(ybuf, batch, gmean, grstd, lnw, lnb, hbOut);
}

extern "C" void kernel_launch(void* const* d_in, const int* in_sizes, int n_in,
                              void* d_out, int out_size, void* d_ws, size_t ws_size,
                              hipStream_t stream)
{
    const float* x_visual = (const float*)d_in[0];
    const float* x_geom   = (const float*)d_in[1];
    const float* x_prior  = (const float*)d_in[2];
    const float* vis_w  = (const float*)d_in[3];
    const float* vis_b  = (const float*)d_in[4];
    const float* vis_lw = (const float*)d_in[5];
    const float* vis_lb = (const float*)d_in[6];
    const float* geom_w  = (const float*)d_in[7];
    const float* geom_b  = (const float*)d_in[8];
    const float* geom_lw = (const float*)d_in[9];
    const float* geom_lb = (const float*)d_in[10];
    const float* prior_w  = (const float*)d_in[11];
    const float* prior_b  = (const float*)d_in[12];
    const float* prior_lw = (const float*)d_in[13];
    const float* prior_lb = (const float*)d_in[14];
    const float* r1_w = (const float*)d_in[15];
    const float* r1_q = (const float*)d_in[16];
    const float* r1_k = (const float*)d_in[17];
    const float* r1_b = (const float*)d_in[18];
    const float* n1_w = (const float*)d_in[19];
    const float* n1_b = (const float*)d_in[20];
    const float* r2_w = (const float*)d_in[21];
    const float* r2_q = (const float*)d_in[22];
    const float* r2_k = (const float*)d_in[23];
    const float* r2_b = (const float*)d_in[24];
    const float* n2_w = (const float*)d_in[25];
    const float* n2_b = (const float*)d_in[26];
    const float* c_w1 = (const float*)d_in[27];
    const float* c_b1 = (const float*)d_in[28];
    const float* c_w2 = (const float*)d_in[29];
    const float* c_b2 = (const float*)d_in[30];
    const int* ei_o  = (const int*)d_in[31];
    const int* ei_a  = (const int*)d_in[32];
    const int* ei_s  = (const int*)d_in[33];
    const int* batch = (const int*)d_in[34];
    float* out = (float*)d_out;

    char* p = (char*)d_ws;
    auto alloc = [&](size_t bytes) { char* r = p; p += (bytes + 255) & ~(size_t)255; return r; };
    float* h0 = (float*)alloc((size_t)NN * FF * 4);              // encoder pre-LN (f32)
    unsigned short* hbA = (unsigned short*)alloc((size_t)NN * FF * 2);
    unsigned short* hbB = (unsigned short*)alloc((size_t)NN * FF * 2);
    unsigned short* ybuf = (unsigned short*)alloc((size_t)NN * FF * 2);
    unsigned short* xt = (unsigned short*)alloc((size_t)3 * NN * FF * 2);
    unsigned short* wt = (unsigned short*)alloc((size_t)3 * FF * FF * 2);
    float* qkbuf = (float*)alloc((size_t)NN * 48 * 4);
    unsigned short* wqkt = (unsigned short*)alloc((size_t)48 * FF * 2);
    float* t128 = (float*)alloc((size_t)NN * 128 * 4);
    int* deg = (int*)alloc(NN * 4);
    int* rps = (int*)alloc(NN * 4);
    int* fill = (int*)alloc(NN * 4);
    int* elist = (int*)alloc(ETOT * 4);
    int* counter = (int*)alloc(256);
    float* gs1 = (float*)alloc(GG * 4);
    float* gs2 = (float*)alloc(GG * 4);
    float* gcnt = (float*)alloc(GG * 4);
    float* gmean = (float*)alloc(GG * 4);
    float* grstd = (float*)alloc(GG * 4);
    float* est = (float*)alloc(64);
    float* pbuf = (float*)alloc(ERB * 6 * 4);

    // ---- CSR build (once; shared by both layers) ----
    hipMemsetAsync(deg, 0, NN * 4, stream);
    hipMemsetAsync(fill, 0, NN * 4, stream);
    hipMemsetAsync(counter, 0, 4, stream);
    csr_count<<<ETOT / 256, 256, 0, stream>>>(ei_o, ei_a, ei_s, deg);
    csr_alloc<<<NN / 256, 256, 0, stream>>>(deg, counter, rps);
    csr_fill<<<ETOT / 256, 256, 0, stream>>>(ei_o, ei_a, ei_s, rps, fill, elist);

    // ---- per-graph node counts ----
    hipMemsetAsync(gcnt, 0, GG * 4, stream);
    count_nodes<<<NN / 256, 256, 0, stream>>>(batch, gcnt);

    // ---- encoders ----
    transpose_bf<<<(1024 * 128 + 255) / 256, 256, 0, stream>>>(vis_w, wt, 1024, 128, 1024 * 128);
    gemm_mfma<1, false, false><<<dim3(384, 1, 1), 256, 0, stream>>>(
        x_visual, 1024, wt, vis_b, h0, FF, 0, 0);
    gemm_k<1><<<dim3(2, 768, 1), 256, 0, stream>>>(x_geom, 6, geom_w, 128, geom_b, h0 + 128, FF, 128);
    gemm_k<1><<<dim3(2, 768, 1), 256, 0, stream>>>(x_prior, 50, prior_w, 128, prior_b, h0 + 256, FF, 128);
    enc_reduce_stage1<<<ERB, 256, 0, stream>>>(h0, pbuf);
    enc_reduce_stage2<<<1, 64, 0, stream>>>(pbuf, est);
    enc_apply<<<(int)((size_t)NN * FF / 256), 256, 0, stream>>>(
        h0, hbA, est, vis_lw, vis_lb, geom_lw, geom_lb, prior_lw, prior_lb);

    // ---- RGAT layers (bf16 ping-pong hbA -> hbB -> hbA) ----
    rgat_layer(stream, hbA, r1_w, r1_q, r1_k, r1_b, n1_w, n1_b,
               rps, deg, elist, batch, wt, xt, wqkt, qkbuf,
               gs1, gs2, gcnt, gmean, grstd, ybuf, hbB);
    rgat_layer(stream, hbB, r2_w, r2_q, r2_k, r2_b, n2_w, n2_b,
               rps, deg, elist, batch, wt, xt, wqkt, qkbuf,
               gs1, gs2, gcnt, gmean, grstd, ybuf, hbA);

    // ---- classifier ----
    transpose_bf<<<(FF * 128 + 255) / 256, 256, 0, stream>>>(c_w1, wt, FF, 128, FF * 128);
    gemm_mfma<1, true, false><<<dim3(384, 1, 1), 256, 0, stream>>>(
        hbA, FF, wt, c_b1, t128, 128, 0, 0);
    gemm_k<0><<<dim3(1, 768, 1), 256, 0, stream>>>(t128, 128, c_w2, 49, c_b2, out, 49, 49);
}

// Round 10
// 748.245 us; speedup vs baseline: 1.2989x; 1.0445x over previous
//
#include <hip/hip_runtime.h>
#include <hip/hip_bf16.h>

#define NN 49152
#define GG 1024
#define EE 65536
#define ETOT 196608
#define FF 384
#define NEG_SLOPE 0.2f

typedef __attribute__((ext_vector_type(8))) short bf16x8;
typedef __attribute__((ext_vector_type(4))) float f32x4;

__device__ __forceinline__ float wave_sum(float v) {
#pragma unroll
    for (int m = 32; m; m >>= 1) v += __shfl_xor(v, m);
    return v;
}
__device__ __forceinline__ unsigned short f2bf(float f) {
    __hip_bfloat16 b = __float2bfloat16(f);
    return *reinterpret_cast<unsigned short*>(&b);
}
__device__ __forceinline__ float bflo(unsigned u) { return __uint_as_float(u << 16); }
__device__ __forceinline__ float bfhi(unsigned u) { return __uint_as_float(u & 0xffff0000u); }
__device__ __forceinline__ unsigned pk2(float lo, float hi) {
    return ((unsigned)f2bf(hi) << 16) | (unsigned)f2bf(lo);
}

__device__ __forceinline__ void gload_lds16(const void* g, void* l) {
    __builtin_amdgcn_global_load_lds(
        (const __attribute__((address_space(1))) unsigned int*)g,
        (__attribute__((address_space(3))) unsigned int*)l, 16, 0, 0);
}

// ================= MFMA bf16 GEMM: C = act(A @ Bt^T + bias) =================
// Grid: x = M-tiles, y = N-tiles, z = batch (A-tile sharers land on one XCD).
__device__ __forceinline__ int swz(int row, int c16) {
    return row * 64 + ((c16 ^ ((row >> 1) & 3)) << 4);
}

template <int ACT, bool ABF, bool OBF>
__global__ __launch_bounds__(256) void gemm_mfma(
    const void* __restrict__ Ag, int K,
    const unsigned short* __restrict__ Btg,
    const float* __restrict__ bias,
    void* __restrict__ Cg, int ldc,
    size_t bzs, size_t czs)
{
    __shared__ __align__(16) char As[8192];
    __shared__ __align__(16) char Bs[8192];
    const unsigned short* Bt = Btg + (size_t)blockIdx.z * bzs;
    int t = threadIdx.x;
    int bm = blockIdx.x << 7, bn = blockIdx.y << 7;
    int lane = t & 63, wid = t >> 6, wr = wid >> 1, wc = wid & 1;
    f32x4 acc[4][4] = {};
    int ktn = K >> 5;
    for (int kt = 0; kt < ktn; ++kt) {
        int k0 = kt << 5;
#pragma unroll
        for (int ii = 0; ii < 2; ++ii) {
            int id = t + (ii << 8);
            int row = id >> 2, c = id & 3;
            int csrc = c ^ ((row >> 1) & 3);
            size_t ldsoff = (size_t)((wid << 10) + (ii << 12));
            if (ABF) {
                const unsigned short* srcA = (const unsigned short*)Ag + (size_t)(bm + row) * K + k0 + csrc * 8;
                gload_lds16(srcA, As + ldsoff);
            } else {
                const float* srcA = (const float*)Ag + (size_t)(bm + row) * K + k0 + c * 8;
                float4 a0 = *(const float4*)srcA;
                float4 a1 = *(const float4*)(srcA + 4);
                union { unsigned short u[8]; int4 v; } P;
                P.u[0] = f2bf(a0.x); P.u[1] = f2bf(a0.y); P.u[2] = f2bf(a0.z); P.u[3] = f2bf(a0.w);
                P.u[4] = f2bf(a1.x); P.u[5] = f2bf(a1.y); P.u[6] = f2bf(a1.z); P.u[7] = f2bf(a1.w);
                *(int4*)(As + swz(row, c)) = P.v;
            }
            const unsigned short* srcB = Bt + (size_t)(bn + row) * K + k0 + csrc * 8;
            gload_lds16(srcB, Bs + ldsoff);
        }
        __syncthreads();
        int c16 = lane >> 4;
        bf16x8 af[4], bfr[4];
#pragma unroll
        for (int m = 0; m < 4; ++m)
            af[m] = *(const bf16x8*)(As + swz((wr << 6) + (m << 4) + (lane & 15), c16));
#pragma unroll
        for (int n = 0; n < 4; ++n)
            bfr[n] = *(const bf16x8*)(Bs + swz((wc << 6) + (n << 4) + (lane & 15), c16));
#pragma unroll
        for (int m = 0; m < 4; ++m)
#pragma unroll
            for (int n = 0; n < 4; ++n)
                acc[m][n] = __builtin_amdgcn_mfma_f32_16x16x32_bf16(af[m], bfr[n], acc[m][n], 0, 0, 0);
        __syncthreads();
    }
#pragma unroll
    for (int m = 0; m < 4; ++m) {
#pragma unroll
        for (int n = 0; n < 4; ++n) {
            int row0 = bm + (wr << 6) + (m << 4) + ((lane >> 4) << 2);
            int col = bn + (wc << 6) + (n << 4) + (lane & 15);
            float bv = bias ? bias[col] : 0.f;
#pragma unroll
            for (int j = 0; j < 4; ++j) {
                float v = acc[m][n][j] + bv;
                if (ACT == 1) v = fmaxf(v, 0.f);
                if (OBF) {
                    unsigned short* C = (unsigned short*)Cg + (size_t)blockIdx.z * czs;
                    C[(size_t)(row0 + j) * ldc + col] = f2bf(v);
                } else {
                    float* C = (float*)Cg + (size_t)blockIdx.z * czs;
                    C[(size_t)(row0 + j) * ldc + col] = v;
                }
            }
        }
    }
}

// ================= f32-input fallback GEMM (small K / small N), optional bf16 out =================
template <int ACT, bool OBF>
__global__ __launch_bounds__(256) void gemm_k(
    const float* __restrict__ A, int K,
    const float* __restrict__ W, int Jw,
    const float* __restrict__ bias,
    void* __restrict__ Cg, int ldc, int jmax)
{
    __shared__ float Ash[16][64];
    __shared__ float Bsh[16][68];
    int tid = threadIdx.x;
    int bj = blockIdx.x << 6;
    int bm = blockIdx.y << 6;
    int tx = tid & 15, ty = tid >> 4;
    float acc[4][4] = {};
    int ktn = (K + 15) >> 4;
    int ar = tid >> 2;
    int aks = (tid & 3) << 2;
    int wk = tid >> 4;
    int wjs = (tid & 15) << 2;
    for (int kt = 0; kt < ktn; ++kt) {
        int k0 = kt << 4;
        const float* Ap = A + (size_t)(bm + ar) * K + k0 + aks;
#pragma unroll
        for (int i = 0; i < 4; ++i) {
            int k = k0 + aks + i;
            Ash[aks + i][ar] = (k < K) ? Ap[i] : 0.f;
        }
        const float* Wp = W + (size_t)(k0 + wk) * Jw + bj + wjs;
        bool kok = (k0 + wk) < K;
#pragma unroll
        for (int i = 0; i < 4; ++i) {
            int j = bj + wjs + i;
            Bsh[wk][wjs + i] = (kok && j < jmax) ? Wp[i] : 0.f;
        }
        __syncthreads();
#pragma unroll
        for (int kk = 0; kk < 16; ++kk) {
            const float4 av = *reinterpret_cast<const float4*>(&Ash[kk][ty << 2]);
            const float4 bv = *reinterpret_cast<const float4*>(&Bsh[kk][tx << 2]);
            float aa[4] = {av.x, av.y, av.z, av.w};
            float bb[4] = {bv.x, bv.y, bv.z, bv.w};
#pragma unroll
            for (int i = 0; i < 4; ++i)
#pragma unroll
                for (int j = 0; j < 4; ++j)
                    acc[i][j] = fmaf(aa[i], bb[j], acc[i][j]);
        }
        __syncthreads();
    }
#pragma unroll
    for (int i = 0; i < 4; ++i) {
        int row = bm + (ty << 2) + i;
#pragma unroll
        for (int j = 0; j < 4; ++j) {
            int col = bj + (tx << 2) + j;
            if (col < jmax) {
                float v = acc[i][j];
                if (bias) v += bias[col];
                if (ACT == 1) v = fmaxf(v, 0.f);
                if (OBF) ((unsigned short*)Cg)[(size_t)row * ldc + col] = f2bf(v);
                else     ((float*)Cg)[(size_t)row * ldc + col] = v;
            }
        }
    }
}

// ================= weight transpose + bf16 convert: Wt[z][n][k] = W[z][k][n] =================
__global__ void transpose_bf(const float* __restrict__ W, unsigned short* __restrict__ Wt,
                             int K, int N, int total) {
    int i = blockIdx.x * 256 + threadIdx.x;
    if (i >= total) return;
    int kn = K * N;
    int z = i / kn, rem = i - z * kn;
    int k = rem / N, n = rem - k * N;
    Wt[(size_t)z * kn + (size_t)n * K + k] = f2bf(W[i]);
}

// ================= wqkt[r*16 + qk*8 + h][f] = sum_c rw[r][f][c] * (qk?k:q)[c][h] =================
__global__ __launch_bounds__(256) void wqk_prep(
    const float* __restrict__ rw, const float* __restrict__ q, const float* __restrict__ k,
    unsigned short* __restrict__ wqkt)
{
    __shared__ float qsT[16 * 384];
    int t = threadIdx.x;
    int r = blockIdx.x, ftile = blockIdx.y;
    for (int idx = t; idx < 384 * 16; idx += 256) {
        int c = idx >> 4, j = idx & 15;
        qsT[j * 384 + c] = (j < 8) ? q[c * 8 + j] : k[c * 8 + j - 8];
    }
    __syncthreads();
    int j = t & 15, fi = t >> 4;
    const float4* q4 = (const float4*)(qsT + j * 384);
#pragma unroll
    for (int rr = 0; rr < 4; ++rr) {
        int f = ftile * 64 + fi * 4 + rr;
        const float4* a4 = (const float4*)(rw + (size_t)r * FF * FF + (size_t)f * FF);
        float dot = 0.f;
        for (int c4 = 0; c4 < 96; ++c4) {
            float4 a = a4[c4], b = q4[c4];
            dot += a.x * b.x + a.y * b.y + a.z * b.z + a.w * b.w;
        }
        wqkt[(size_t)(r * 16 + j) * FF + f] = f2bf(dot);
    }
}

// ================= CSR build =================
__global__ void csr_count(const int* __restrict__ eo, const int* __restrict__ ea,
                          const int* __restrict__ es, int* __restrict__ deg) {
    int e = blockIdx.x * 256 + threadIdx.x;
    if (e >= ETOT) return;
    int et = e >> 16, le = e & 65535;
    const int* ei = et == 0 ? eo : (et == 1 ? ea : es);
    atomicAdd(&deg[ei[EE + le]], 1);
}
__global__ void csr_alloc(const int* __restrict__ deg, int* __restrict__ counter,
                          int* __restrict__ rps) {
    int n = blockIdx.x * 256 + threadIdx.x;
    int lane = threadIdx.x & 63;
    int d = (n < NN) ? deg[n] : 0;
    int x = d;
#pragma unroll
    for (int off = 1; off < 64; off <<= 1) {
        int y = __shfl_up(x, off);
        if (lane >= off) x += y;
    }
    int total = __shfl(x, 63);
    int base = 0;
    if (lane == 63) base = atomicAdd(counter, total);
    base = __shfl(base, 63);
    if (n < NN) rps[n] = base + x - d;
}
__global__ void csr_fill(const int* __restrict__ eo, const int* __restrict__ ea,
                         const int* __restrict__ es, const int* __restrict__ rps,
                         int* __restrict__ fill, int* __restrict__ elist) {
    int e = blockIdx.x * 256 + threadIdx.x;
    if (e >= ETOT) return;
    int et = e >> 16, le = e & 65535;
    const int* ei = et == 0 ? eo : (et == 1 ? ea : es);
    int src = ei[le], dst = ei[EE + le];
    int pos = rps[dst] + atomicAdd(&fill[dst], 1);
    elist[pos] = (et << 16) | src;
}

// ================= misc =================
__global__ void count_nodes(const int* __restrict__ batch, float* __restrict__ gcnt) {
    int n = blockIdx.x * 256 + threadIdx.x;
    if (n < NN) atomicAdd(&gcnt[batch[n]], 1.f);
}

// ================= encoder stats over bf16 h: two-stage, no atomics =================
#define ERB 512
__global__ __launch_bounds__(256) void enc_reduce_stage1(const unsigned short* __restrict__ hb, float* __restrict__ pbuf) {
    __shared__ float part[4][6];
    float a1 = 0.f, a2 = 0.f, b1 = 0.f, b2 = 0.f, c1 = 0.f, c2 = 0.f;
    const uint4* h8 = (const uint4*)hb;
    int total8 = NN * FF / 8;
    for (int i = blockIdx.x * 256 + threadIdx.x; i < total8; i += ERB * 256) {
        uint4 v = h8[i];
        float e0 = bflo(v.x), e1 = bfhi(v.x), e2 = bflo(v.y), e3 = bfhi(v.y);
        float e4 = bflo(v.z), e5 = bfhi(v.z), e6 = bflo(v.w), e7 = bfhi(v.w);
        float s1 = e0 + e1 + e2 + e3 + e4 + e5 + e6 + e7;
        float s2 = e0*e0 + e1*e1 + e2*e2 + e3*e3 + e4*e4 + e5*e5 + e6*e6 + e7*e7;
        int enc = (i % 48) >> 4;  // 8-elem chunk within row: 0-15/16-31/32-47
        if (enc == 0)      { a1 += s1; a2 += s2; }
        else if (enc == 1) { b1 += s1; b2 += s2; }
        else               { c1 += s1; c2 += s2; }
    }
    a1 = wave_sum(a1); a2 = wave_sum(a2);
    b1 = wave_sum(b1); b2 = wave_sum(b2);
    c1 = wave_sum(c1); c2 = wave_sum(c2);
    int w = threadIdx.x >> 6;
    if ((threadIdx.x & 63) == 0) {
        part[w][0] = a1; part[w][1] = a2; part[w][2] = b1;
        part[w][3] = b2; part[w][4] = c1; part[w][5] = c2;
    }
    __syncthreads();
    if (threadIdx.x < 6) {
        float s = part[0][threadIdx.x] + part[1][threadIdx.x] + part[2][threadIdx.x] + part[3][threadIdx.x];
        pbuf[blockIdx.x * 6 + threadIdx.x] = s;
    }
}

__global__ void enc_reduce_stage2(const float* __restrict__ pbuf, float* __restrict__ est) {
    int lane = threadIdx.x;
    float s[6] = {};
    for (int b = lane; b < ERB; b += 64)
#pragma unroll
        for (int j = 0; j < 6; ++j) s[j] += pbuf[b * 6 + j];
#pragma unroll
    for (int j = 0; j < 6; ++j) {
        float v = wave_sum(s[j]);
        if (lane == 0) est[j] = v;
    }
    __syncthreads();
    if (lane < 3) {
        float cnt = (float)NN * 128.f;
        float mean = est[2 * lane] / cnt;
        float var = est[2 * lane + 1] / cnt - mean * mean;
        var = fmaxf(var, 0.f);
        est[6 + 2 * lane] = mean;
        est[7 + 2 * lane] = 1.f / (sqrtf(var) + 1e-5f);
    }
}

__global__ __launch_bounds__(256) void enc_apply(
    unsigned short* __restrict__ hb, const float* __restrict__ est,
    const float* __restrict__ lw0, const float* __restrict__ lb0,
    const float* __restrict__ lw1, const float* __restrict__ lb1,
    const float* __restrict__ lw2, const float* __restrict__ lb2)
{
    long gt = (long)blockIdx.x * 256 + threadIdx.x;
    if (gt >= (long)NN * FF) return;
    int f = (int)(gt % FF);
    int enc = f >> 7, j = f & 127;
    const float* lw = enc == 0 ? lw0 : (enc == 1 ? lw1 : lw2);
    const float* lb = enc == 0 ? lb0 : (enc == 1 ? lb1 : lb2);
    float mean = est[6 + 2 * enc], sc = est[7 + 2 * enc];
    float v = (bflo((unsigned)hb[gt]) - mean) * sc * lw[j] + lb[j];  // bflo does the <<16
    hb[gt] = f2bf(v);
}

// ================= qkbuf via MFMA: [N,384] @ [384,48] from h directly =================
__global__ __launch_bounds__(256) void qk48_mfma(
    const unsigned short* __restrict__ hb,
    const unsigned short* __restrict__ wqkt,
    float* __restrict__ qkbuf)
{
    __shared__ __align__(16) unsigned short wlds[48 * 392];
    int t = threadIdx.x;
    for (int idx = t; idx < 48 * 192; idx += 256) {
        int row = idx / 192, dw = idx - row * 192;
        *((unsigned*)(wlds + row * 392) + dw) = ((const unsigned*)wqkt)[row * 192 + dw];
    }
    __syncthreads();
    int lane = t & 63, wid = t >> 6;
    int col = lane & 15, kq = lane >> 4;
    int tile = blockIdx.x * 4 + wid;
    const unsigned short* arow = hb + (size_t)(tile * 16 + col) * FF + kq * 8;
    f32x4 acc0 = {}, acc1 = {}, acc2 = {};
#pragma unroll
    for (int kt = 0; kt < 12; ++kt) {
        bf16x8 af = *(const bf16x8*)(arow + kt * 32);
        bf16x8 b0 = *(const bf16x8*)(wlds + (0 * 16 + col) * 392 + kt * 32 + kq * 8);
        bf16x8 b1 = *(const bf16x8*)(wlds + (1 * 16 + col) * 392 + kt * 32 + kq * 8);
        bf16x8 b2 = *(const bf16x8*)(wlds + (2 * 16 + col) * 392 + kt * 32 + kq * 8);
        acc0 = __builtin_amdgcn_mfma_f32_16x16x32_bf16(af, b0, acc0, 0, 0, 0);
        acc1 = __builtin_amdgcn_mfma_f32_16x16x32_bf16(af, b1, acc1, 0, 0, 0);
        acc2 = __builtin_amdgcn_mfma_f32_16x16x32_bf16(af, b2, acc2, 0, 0, 0);
    }
    int row0 = kq << 2;
#pragma unroll
    for (int j = 0; j < 4; ++j) {
        size_t node = (size_t)tile * 16 + row0 + j;
        qkbuf[node * 48 + 0 + col]  = acc0[j];
        qkbuf[node * 48 + 16 + col] = acc1[j];
        qkbuf[node * 48 + 32 + col] = acc2[j];
    }
}

// ================= single-pass softmax (no max: |alpha| small) + gather + elu + residual + stats =================
__global__ __launch_bounds__(256) void gather_fused(
    const int* __restrict__ rps, const int* __restrict__ deg, const int* __restrict__ elist,
    const float* __restrict__ qkbuf, const unsigned short* __restrict__ xt,
    const unsigned short* __restrict__ hbin, const float* __restrict__ rb, const int* __restrict__ batch,
    float* __restrict__ gs1, float* __restrict__ gs2, unsigned short* __restrict__ ybuf)
{
    int node = blockIdx.x * 4 + (threadIdx.x >> 6);
    int lane = threadIdx.x & 63;
    int d = deg[node], rp = rps[node];
    int head = lane >> 3;
    float qd0 = qkbuf[(size_t)node * 48 + 0 + head];
    float qd1 = qkbuf[(size_t)node * 48 + 16 + head];
    float qd2 = qkbuf[(size_t)node * 48 + 32 + head];
    float s = 0.f;
    float acc0 = 0.f, acc1 = 0.f, acc2 = 0.f, acc3 = 0.f, acc4 = 0.f, acc5 = 0.f;
    for (int e = 0; e < d; ++e) {
        int packed = elist[rp + e];
        int et = packed >> 16, src = packed & 0xFFFF;
        const unsigned* xr = (const unsigned*)(xt + ((size_t)et * NN + src) * FF) + lane * 3;
        unsigned u0 = xr[0], u1 = xr[1], u2 = xr[2];
        float qd = et == 0 ? qd0 : (et == 1 ? qd1 : qd2);
        float a = qd + qkbuf[(size_t)src * 48 + et * 16 + 8 + head];
        a = a >= 0.f ? a : NEG_SLOPE * a;
        float pw = __expf(a);   // alpha bounded => safe without max shift
        s += pw;
        acc0 = fmaf(pw, bflo(u0), acc0); acc1 = fmaf(pw, bfhi(u0), acc1);
        acc2 = fmaf(pw, bflo(u1), acc2); acc3 = fmaf(pw, bfhi(u1), acc3);
        acc4 = fmaf(pw, bflo(u2), acc4); acc5 = fmaf(pw, bfhi(u2), acc5);
    }
    float inv = 1.f / (s + 1e-16f);
    const unsigned* hr = (const unsigned*)(hbin + (size_t)node * FF) + lane * 3;
    unsigned h0u = hr[0], h1u = hr[1], h2u = hr[2];
    float hv[6] = {bflo(h0u), bfhi(h0u), bflo(h1u), bfhi(h1u), bflo(h2u), bfhi(h2u)};
    float av[6] = {acc0, acc1, acc2, acc3, acc4, acc5};
    int f0 = lane * 6;
    float s1 = 0.f, s2 = 0.f;
    float yv[6];
#pragma unroll
    for (int i = 0; i < 6; ++i) {
        float mv = av[i] * inv + rb[f0 + i];
        float e = mv > 0.f ? mv : (__expf(mv) - 1.f);
        float y = hv[i] + e;
        yv[i] = y;
        s1 += y; s2 += y * y;
    }
    unsigned* yrow = (unsigned*)(ybuf + (size_t)node * FF) + lane * 3;
    yrow[0] = pk2(yv[0], yv[1]);
    yrow[1] = pk2(yv[2], yv[3]);
    yrow[2] = pk2(yv[4], yv[5]);
    s1 = wave_sum(s1);
    s2 = wave_sum(s2);
    if (lane == 0) {
        int g = batch[node];
        atomicAdd(&gs1[g], s1);
        atomicAdd(&gs2[g], s2);
    }
}

// ================= LN apply with inline per-graph finalize =================
__global__ __launch_bounds__(256) void ln_apply(
    const unsigned short* __restrict__ y, const int* __restrict__ batch,
    const float* __restrict__ gcnt, const float* __restrict__ gs1, const float* __restrict__ gs2,
    const float* __restrict__ w, const float* __restrict__ b,
    unsigned short* __restrict__ hbOut)
{
    long gt = (long)blockIdx.x * 256 + threadIdx.x;
    int n = (int)(gt >> 6);
    if (n >= NN) return;
    int lane = (int)(gt & 63);
    int f0 = lane * 6;
    int g = batch[n];
    float cnt = fmaxf(gcnt[g], 1.f) * (float)FF;
    float mean = gs1[g] / cnt;
    float var = fmaxf(gs2[g] / cnt - mean * mean, 0.f);
    float rs = 1.f / sqrtf(var + 1e-5f);
    const unsigned* yr = (const unsigned*)(y + (size_t)n * FF) + lane * 3;
    unsigned u0 = yr[0], u1 = yr[1], u2 = yr[2];
    float yv[6] = {bflo(u0), bfhi(u0), bflo(u1), bfhi(u1), bflo(u2), bfhi(u2)};
    float ov[6];
#pragma unroll
    for (int i = 0; i < 6; ++i)
        ov[i] = (yv[i] - mean) * rs * w[f0 + i] + b[f0 + i];
    unsigned* orow = (unsigned*)(hbOut + (size_t)n * FF) + lane * 3;
    orow[0] = pk2(ov[0], ov[1]);
    orow[1] = pk2(ov[2], ov[3]);
    orow[2] = pk2(ov[4], ov[5]);
}

// ================= host-side layer driver =================
static void rgat_layer(hipStream_t stream,
    const unsigned short* hbIn,
    const float* rw, const float* rq, const float* rk, const float* rb,
    const float* lnw, const float* lnb,
    const int* rps, const int* deg, const int* elist, const int* batch,
    unsigned short* wt, unsigned short* xt, unsigned short* wqkt, float* qkbuf,
    float* gsbuf, const float* gcnt,
    unsigned short* ybuf, unsigned short* hbOut)
{
    hipMemsetAsync(gsbuf, 0, 2 * GG * 4, stream);
    int tt = 3 * FF * FF;
    transpose_bf<<<(tt + 255) / 256, 256, 0, stream>>>(rw, wt, FF, FF, tt);
    wqk_prep<<<dim3(3, 6), 256, 0, stream>>>(rw, rq, rk, wqkt);
    gemm_mfma<0, true, true><<<dim3(384, 3, 3), 256, 0, stream>>>(
        hbIn, FF, wt, nullptr, xt, FF, (size_t)FF * FF, (size_t)NN * FF);
    qk48_mfma<<<NN / 64, 256, 0, stream>>>(hbIn, wqkt, qkbuf);
    gather_fused<<<NN / 4, 256, 0, stream>>>(rps, deg, elist, qkbuf, xt, hbIn, rb, batch,
                                             gsbuf, gsbuf + GG, ybuf);
    ln_apply<<<NN / 4, 256, 0, stream>>>(ybuf, batch, gcnt, gsbuf, gsbuf + GG, lnw, lnb, hbOut);
}

extern "C" void kernel_launch(void* const* d_in, const int* in_sizes, int n_in,
                              void* d_out, int out_size, void* d_ws, size_t ws_size,
                              hipStream_t stream)
{
    const float* x_visual = (const float*)d_in[0];
    const float* x_geom   = (const float*)d_in[1];
    const float* x_prior  = (const float*)d_in[2];
    const float* vis_w  = (const float*)d_in[3];
    const float* vis_b  = (const float*)d_in[4];
    const float* vis_lw = (const float*)d_in[5];
    const float* vis_lb = (const float*)d_in[6];
    const float* geom_w  = (const float*)d_in[7];
    const float* geom_b  = (const float*)d_in[8];
    const float* geom_lw = (const float*)d_in[9];
    const float* geom_lb = (const float*)d_in[10];
    const float* prior_w  = (const float*)d_in[11];
    const float* prior_b  = (const float*)d_in[12];
    const float* prior_lw = (const float*)d_in[13];
    const float* prior_lb = (const float*)d_in[14];
    const float* r1_w = (const float*)d_in[15];
    const float* r1_q = (const float*)d_in[16];
    const float* r1_k = (const float*)d_in[17];
    const float* r1_b = (const float*)d_in[18];
    const float* n1_w = (const float*)d_in[19];
    const float* n1_b = (const float*)d_in[20];
    const float* r2_w = (const float*)d_in[21];
    const float* r2_q = (const float*)d_in[22];
    const float* r2_k = (const float*)d_in[23];
    const float* r2_b = (const float*)d_in[24];
    const float* n2_w = (const float*)d_in[25];
    const float* n2_b = (const float*)d_in[26];
    const float* c_w1 = (const float*)d_in[27];
    const float* c_b1 = (const float*)d_in[28];
    const float* c_w2 = (const float*)d_in[29];
    const float* c_b2 = (const float*)d_in[30];
    const int* ei_o  = (const int*)d_in[31];
    const int* ei_a  = (const int*)d_in[32];
    const int* ei_s  = (const int*)d_in[33];
    const int* batch = (const int*)d_in[34];
    float* out = (float*)d_out;

    char* p = (char*)d_ws;
    auto alloc = [&](size_t bytes) { char* r = p; p += (bytes + 255) & ~(size_t)255; return r; };
    unsigned short* hbA = (unsigned short*)alloc((size_t)NN * FF * 2);
    unsigned short* hbB = (unsigned short*)alloc((size_t)NN * FF * 2);
    unsigned short* ybuf = (unsigned short*)alloc((size_t)NN * FF * 2);
    unsigned short* xt = (unsigned short*)alloc((size_t)3 * NN * FF * 2);
    unsigned short* wt = (unsigned short*)alloc((size_t)3 * FF * FF * 2);
    float* qkbuf = (float*)alloc((size_t)NN * 48 * 4);
    unsigned short* wqkt = (unsigned short*)alloc((size_t)48 * FF * 2);
    float* t128 = (float*)alloc((size_t)NN * 128 * 4);
    int* degfill = (int*)alloc((size_t)2 * NN * 4);
    int* deg = degfill;
    int* fill = degfill + NN;
    int* rps = (int*)alloc(NN * 4);
    int* elist = (int*)alloc(ETOT * 4);
    int* counter = (int*)alloc(256);
    float* gsbuf = (float*)alloc((size_t)2 * GG * 4);
    float* gcnt = (float*)alloc(GG * 4);
    float* est = (float*)alloc(64);
    float* pbuf = (float*)alloc(ERB * 6 * 4);

    // ---- CSR build (once; shared by both layers) ----
    hipMemsetAsync(degfill, 0, (size_t)2 * NN * 4, stream);
    hipMemsetAsync(counter, 0, 4, stream);
    csr_count<<<ETOT / 256, 256, 0, stream>>>(ei_o, ei_a, ei_s, deg);
    csr_alloc<<<NN / 256, 256, 0, stream>>>(deg, counter, rps);
    csr_fill<<<ETOT / 256, 256, 0, stream>>>(ei_o, ei_a, ei_s, rps, fill, elist);

    // ---- per-graph node counts ----
    hipMemsetAsync(gcnt, 0, GG * 4, stream);
    count_nodes<<<NN / 256, 256, 0, stream>>>(batch, gcnt);

    // ---- encoders (all-bf16 h) ----
    transpose_bf<<<(1024 * 128 + 255) / 256, 256, 0, stream>>>(vis_w, wt, 1024, 128, 1024 * 128);
    gemm_mfma<1, false, true><<<dim3(384, 1, 1), 256, 0, stream>>>(
        x_visual, 1024, wt, vis_b, hbA, FF, 0, 0);
    gemm_k<1, true><<<dim3(2, 768, 1), 256, 0, stream>>>(x_geom, 6, geom_w, 128, geom_b, hbA + 128, FF, 128);
    gemm_k<1, true><<<dim3(2, 768, 1), 256, 0, stream>>>(x_prior, 50, prior_w, 128, prior_b, hbA + 256, FF, 128);
    enc_reduce_stage1<<<ERB, 256, 0, stream>>>(hbA, pbuf);
    enc_reduce_stage2<<<1, 64, 0, stream>>>(pbuf, est);
    enc_apply<<<(int)((size_t)NN * FF / 256), 256, 0, stream>>>(
        hbA, est, vis_lw, vis_lb, geom_lw, geom_lb, prior_lw, prior_lb);

    // ---- RGAT layers (bf16 ping-pong hbA -> hbB -> hbA) ----
    rgat_layer(stream, hbA, r1_w, r1_q, r1_k, r1_b, n1_w, n1_b,
               rps, deg, elist, batch, wt, xt, wqkt, qkbuf, gsbuf, gcnt, ybuf, hbB);
    rgat_layer(stream, hbB, r2_w, r2_q, r2_k, r2_b, n2_w, n2_b,
               rps, deg, elist, batch, wt, xt, wqkt, qkbuf, gsbuf, gcnt, ybuf, hbA);

    // ---- classifier ----
    transpose_bf<<<(FF * 128 + 255) / 256, 256, 0, stream>>>(c_w1, wt, FF, 128, FF * 128);
    gemm_mfma<1, true, false><<<dim3(384, 1, 1), 256, 0, stream>>>(
        hbA, FF, wt, c_b1, t128, 128, 0, 0);
    gemm_k<0, false><<<dim3(1, 768, 1), 256, 0, stream>>>(t128, 128, c_w2, 49, c_b2, out, 49, 49);
}

// Round 11
// 700.591 us; speedup vs baseline: 1.3872x; 1.0680x over previous
//
#include <hip/hip_runtime.h>
#include <hip/hip_bf16.h>

#define NN 49152
#define GG 1024
#define EE 65536
#define ETOT 196608
#define FF 384
#define NEG_SLOPE 0.2f

typedef __attribute__((ext_vector_type(8))) short bf16x8;
typedef __attribute__((ext_vector_type(4))) float f32x4;

__device__ __forceinline__ float wave_sum(float v) {
#pragma unroll
    for (int m = 32; m; m >>= 1) v += __shfl_xor(v, m);
    return v;
}
__device__ __forceinline__ unsigned short f2bf(float f) {
    __hip_bfloat16 b = __float2bfloat16(f);
    return *reinterpret_cast<unsigned short*>(&b);
}
__device__ __forceinline__ float bflo(unsigned u) { return __uint_as_float(u << 16); }
__device__ __forceinline__ float bfhi(unsigned u) { return __uint_as_float(u & 0xffff0000u); }
__device__ __forceinline__ unsigned pk2(float lo, float hi) {
    return ((unsigned)f2bf(hi) << 16) | (unsigned)f2bf(lo);
}

__device__ __forceinline__ void gload_lds16(const void* g, void* l) {
    __builtin_amdgcn_global_load_lds(
        (const __attribute__((address_space(1))) unsigned int*)g,
        (__attribute__((address_space(3))) unsigned int*)l, 16, 0, 0);
}

// ================= MFMA bf16 GEMM: C = act(A @ Bt^T + bias) =================
// Grid: x = M-tiles, y = N-tiles, z = batch (A-tile sharers land on one XCD).
__device__ __forceinline__ int swz(int row, int c16) {
    return row * 64 + ((c16 ^ ((row >> 1) & 3)) << 4);
}

template <int ACT, bool ABF, bool OBF>
__global__ __launch_bounds__(256) void gemm_mfma(
    const void* __restrict__ Ag, int K,
    const unsigned short* __restrict__ Btg,
    const float* __restrict__ bias,
    void* __restrict__ Cg, int ldc,
    size_t bzs, size_t czs)
{
    __shared__ __align__(16) char As[8192];
    __shared__ __align__(16) char Bs[8192];
    const unsigned short* Bt = Btg + (size_t)blockIdx.z * bzs;
    int t = threadIdx.x;
    int bm = blockIdx.x << 7, bn = blockIdx.y << 7;
    int lane = t & 63, wid = t >> 6, wr = wid >> 1, wc = wid & 1;
    f32x4 acc[4][4] = {};
    int ktn = K >> 5;
    for (int kt = 0; kt < ktn; ++kt) {
        int k0 = kt << 5;
#pragma unroll
        for (int ii = 0; ii < 2; ++ii) {
            int id = t + (ii << 8);
            int row = id >> 2, c = id & 3;
            int csrc = c ^ ((row >> 1) & 3);
            size_t ldsoff = (size_t)((wid << 10) + (ii << 12));
            if (ABF) {
                const unsigned short* srcA = (const unsigned short*)Ag + (size_t)(bm + row) * K + k0 + csrc * 8;
                gload_lds16(srcA, As + ldsoff);
            } else {
                const float* srcA = (const float*)Ag + (size_t)(bm + row) * K + k0 + c * 8;
                float4 a0 = *(const float4*)srcA;
                float4 a1 = *(const float4*)(srcA + 4);
                union { unsigned short u[8]; int4 v; } P;
                P.u[0] = f2bf(a0.x); P.u[1] = f2bf(a0.y); P.u[2] = f2bf(a0.z); P.u[3] = f2bf(a0.w);
                P.u[4] = f2bf(a1.x); P.u[5] = f2bf(a1.y); P.u[6] = f2bf(a1.z); P.u[7] = f2bf(a1.w);
                *(int4*)(As + swz(row, c)) = P.v;
            }
            const unsigned short* srcB = Bt + (size_t)(bn + row) * K + k0 + csrc * 8;
            gload_lds16(srcB, Bs + ldsoff);
        }
        __syncthreads();
        int c16 = lane >> 4;
        bf16x8 af[4], bfr[4];
#pragma unroll
        for (int m = 0; m < 4; ++m)
            af[m] = *(const bf16x8*)(As + swz((wr << 6) + (m << 4) + (lane & 15), c16));
#pragma unroll
        for (int n = 0; n < 4; ++n)
            bfr[n] = *(const bf16x8*)(Bs + swz((wc << 6) + (n << 4) + (lane & 15), c16));
#pragma unroll
        for (int m = 0; m < 4; ++m)
#pragma unroll
            for (int n = 0; n < 4; ++n)
                acc[m][n] = __builtin_amdgcn_mfma_f32_16x16x32_bf16(af[m], bfr[n], acc[m][n], 0, 0, 0);
        __syncthreads();
    }
#pragma unroll
    for (int m = 0; m < 4; ++m) {
#pragma unroll
        for (int n = 0; n < 4; ++n) {
            int row0 = bm + (wr << 6) + (m << 4) + ((lane >> 4) << 2);
            int col = bn + (wc << 6) + (n << 4) + (lane & 15);
            float bv = bias ? bias[col] : 0.f;
#pragma unroll
            for (int j = 0; j < 4; ++j) {
                float v = acc[m][n][j] + bv;
                if (ACT == 1) v = fmaxf(v, 0.f);
                if (OBF) {
                    unsigned short* C = (unsigned short*)Cg + (size_t)blockIdx.z * czs;
                    C[(size_t)(row0 + j) * ldc + col] = f2bf(v);
                } else {
                    float* C = (float*)Cg + (size_t)blockIdx.z * czs;
                    C[(size_t)(row0 + j) * ldc + col] = v;
                }
            }
        }
    }
}

// ================= f32-input fallback GEMM (small K / small N), optional bf16 out =================
template <int ACT, bool OBF>
__global__ __launch_bounds__(256) void gemm_k(
    const float* __restrict__ A, int K,
    const float* __restrict__ W, int Jw,
    const float* __restrict__ bias,
    void* __restrict__ Cg, int ldc, int jmax)
{
    __shared__ float Ash[16][64];
    __shared__ float Bsh[16][68];
    int tid = threadIdx.x;
    int bj = blockIdx.x << 6;
    int bm = blockIdx.y << 6;
    int tx = tid & 15, ty = tid >> 4;
    float acc[4][4] = {};
    int ktn = (K + 15) >> 4;
    int ar = tid >> 2;
    int aks = (tid & 3) << 2;
    int wk = tid >> 4;
    int wjs = (tid & 15) << 2;
    for (int kt = 0; kt < ktn; ++kt) {
        int k0 = kt << 4;
        const float* Ap = A + (size_t)(bm + ar) * K + k0 + aks;
#pragma unroll
        for (int i = 0; i < 4; ++i) {
            int k = k0 + aks + i;
            Ash[aks + i][ar] = (k < K) ? Ap[i] : 0.f;
        }
        const float* Wp = W + (size_t)(k0 + wk) * Jw + bj + wjs;
        bool kok = (k0 + wk) < K;
#pragma unroll
        for (int i = 0; i < 4; ++i) {
            int j = bj + wjs + i;
            Bsh[wk][wjs + i] = (kok && j < jmax) ? Wp[i] : 0.f;
        }
        __syncthreads();
#pragma unroll
        for (int kk = 0; kk < 16; ++kk) {
            const float4 av = *reinterpret_cast<const float4*>(&Ash[kk][ty << 2]);
            const float4 bv = *reinterpret_cast<const float4*>(&Bsh[kk][tx << 2]);
            float aa[4] = {av.x, av.y, av.z, av.w};
            float bb[4] = {bv.x, bv.y, bv.z, bv.w};
#pragma unroll
            for (int i = 0; i < 4; ++i)
#pragma unroll
                for (int j = 0; j < 4; ++j)
                    acc[i][j] = fmaf(aa[i], bb[j], acc[i][j]);
        }
        __syncthreads();
    }
#pragma unroll
    for (int i = 0; i < 4; ++i) {
        int row = bm + (ty << 2) + i;
#pragma unroll
        for (int j = 0; j < 4; ++j) {
            int col = bj + (tx << 2) + j;
            if (col < jmax) {
                float v = acc[i][j];
                if (bias) v += bias[col];
                if (ACT == 1) v = fmaxf(v, 0.f);
                if (OBF) ((unsigned short*)Cg)[(size_t)row * ldc + col] = f2bf(v);
                else     ((float*)Cg)[(size_t)row * ldc + col] = v;
            }
        }
    }
}

// ================= generic weight transpose + bf16 convert: Wt[z][n][k] = W[z][k][n] =================
__global__ void transpose_bf(const float* __restrict__ W, unsigned short* __restrict__ Wt,
                             int K, int N, int total) {
    int i = blockIdx.x * 256 + threadIdx.x;
    if (i >= total) return;
    int kn = K * N;
    int z = i / kn, rem = i - z * kn;
    int k = rem / N, n = rem - k * N;
    Wt[(size_t)z * kn + (size_t)n * K + k] = f2bf(W[i]);
}

// both layers' relation weights in one launch: 6 z-slices of [384][384]
__global__ void transpose2_bf(const float* __restrict__ W1, const float* __restrict__ W2,
                              unsigned short* __restrict__ Wt1, unsigned short* __restrict__ Wt2) {
    int i = blockIdx.x * 256 + threadIdx.x;
    if (i >= 6 * FF * FF) return;
    int z = i / (FF * FF), rem = i - z * (FF * FF);
    int k = rem / FF, n = rem - k * FF;
    const float* W = (z < 3) ? W1 + (size_t)z * FF * FF : W2 + (size_t)(z - 3) * FF * FF;
    unsigned short* Wt = (z < 3) ? Wt1 + (size_t)z * FF * FF : Wt2 + (size_t)(z - 3) * FF * FF;
    Wt[(size_t)n * FF + k] = f2bf(W[(size_t)k * FF + n]);
}

// ================= wqkt[r*16 + qk*8 + h][f] = sum_c rw[r][f][c] * (qk?k:q)[c][h] =================
// grid (3, 6, 2): (relation, 64-row f-tile, layer)
__global__ __launch_bounds__(256) void wqk_prep2(
    const float* __restrict__ rw1, const float* __restrict__ q1, const float* __restrict__ k1,
    const float* __restrict__ rw2, const float* __restrict__ q2, const float* __restrict__ k2,
    unsigned short* __restrict__ wqkt1, unsigned short* __restrict__ wqkt2)
{
    __shared__ float qsT[16 * 384];
    int t = threadIdx.x;
    int r = blockIdx.x, ftile = blockIdx.y, layer = blockIdx.z;
    const float* rw = layer ? rw2 : rw1;
    const float* q = layer ? q2 : q1;
    const float* k = layer ? k2 : k1;
    unsigned short* wqkt = layer ? wqkt2 : wqkt1;
    for (int idx = t; idx < 384 * 16; idx += 256) {
        int c = idx >> 4, j = idx & 15;
        qsT[j * 384 + c] = (j < 8) ? q[c * 8 + j] : k[c * 8 + j - 8];
    }
    __syncthreads();
    int j = t & 15, fi = t >> 4;
    const float4* q4 = (const float4*)(qsT + j * 384);
#pragma unroll
    for (int rr = 0; rr < 4; ++rr) {
        int f = ftile * 64 + fi * 4 + rr;
        const float4* a4 = (const float4*)(rw + (size_t)r * FF * FF + (size_t)f * FF);
        float dot = 0.f;
        for (int c4 = 0; c4 < 96; ++c4) {
            float4 a = a4[c4], b = q4[c4];
            dot += a.x * b.x + a.y * b.y + a.z * b.z + a.w * b.w;
        }
        wqkt[(size_t)(r * 16 + j) * FF + f] = f2bf(dot);
    }
}

// ================= CSR build =================
__global__ void csr_count(const int* __restrict__ eo, const int* __restrict__ ea,
                          const int* __restrict__ es, int* __restrict__ deg) {
    int e = blockIdx.x * 256 + threadIdx.x;
    if (e >= ETOT) return;
    int et = e >> 16, le = e & 65535;
    const int* ei = et == 0 ? eo : (et == 1 ? ea : es);
    atomicAdd(&deg[ei[EE + le]], 1);
}
// wave-scan allocation + per-graph node count (node-parallel)
__global__ void csr_alloc(const int* __restrict__ deg, int* __restrict__ counter,
                          int* __restrict__ rps, const int* __restrict__ batch,
                          float* __restrict__ gcnt) {
    int n = blockIdx.x * 256 + threadIdx.x;
    int lane = threadIdx.x & 63;
    int d = (n < NN) ? deg[n] : 0;
    int x = d;
#pragma unroll
    for (int off = 1; off < 64; off <<= 1) {
        int y = __shfl_up(x, off);
        if (lane >= off) x += y;
    }
    int total = __shfl(x, 63);
    int base = 0;
    if (lane == 63) base = atomicAdd(counter, total);
    base = __shfl(base, 63);
    if (n < NN) {
        rps[n] = base + x - d;
        atomicAdd(&gcnt[batch[n]], 1.f);
    }
}
__global__ void csr_fill(const int* __restrict__ eo, const int* __restrict__ ea,
                         const int* __restrict__ es, const int* __restrict__ rps,
                         int* __restrict__ fill, int* __restrict__ elist) {
    int e = blockIdx.x * 256 + threadIdx.x;
    if (e >= ETOT) return;
    int et = e >> 16, le = e & 65535;
    const int* ei = et == 0 ? eo : (et == 1 ? ea : es);
    int src = ei[le], dst = ei[EE + le];
    int pos = rps[dst] + atomicAdd(&fill[dst], 1);
    elist[pos] = (et << 16) | src;
}

// ================= encoder stats over bf16 h: two-stage, no atomics =================
#define ERB 512
__global__ __launch_bounds__(256) void enc_reduce_stage1(const unsigned short* __restrict__ hb, float* __restrict__ pbuf) {
    __shared__ float part[4][6];
    float a1 = 0.f, a2 = 0.f, b1 = 0.f, b2 = 0.f, c1 = 0.f, c2 = 0.f;
    const uint4* h8 = (const uint4*)hb;
    int total8 = NN * FF / 8;
    for (int i = blockIdx.x * 256 + threadIdx.x; i < total8; i += ERB * 256) {
        uint4 v = h8[i];
        float e0 = bflo(v.x), e1 = bfhi(v.x), e2 = bflo(v.y), e3 = bfhi(v.y);
        float e4 = bflo(v.z), e5 = bfhi(v.z), e6 = bflo(v.w), e7 = bfhi(v.w);
        float s1 = e0 + e1 + e2 + e3 + e4 + e5 + e6 + e7;
        float s2 = e0*e0 + e1*e1 + e2*e2 + e3*e3 + e4*e4 + e5*e5 + e6*e6 + e7*e7;
        int enc = (i % 48) >> 4;
        if (enc == 0)      { a1 += s1; a2 += s2; }
        else if (enc == 1) { b1 += s1; b2 += s2; }
        else               { c1 += s1; c2 += s2; }
    }
    a1 = wave_sum(a1); a2 = wave_sum(a2);
    b1 = wave_sum(b1); b2 = wave_sum(b2);
    c1 = wave_sum(c1); c2 = wave_sum(c2);
    int w = threadIdx.x >> 6;
    if ((threadIdx.x & 63) == 0) {
        part[w][0] = a1; part[w][1] = a2; part[w][2] = b1;
        part[w][3] = b2; part[w][4] = c1; part[w][5] = c2;
    }
    __syncthreads();
    if (threadIdx.x < 6) {
        float s = part[0][threadIdx.x] + part[1][threadIdx.x] + part[2][threadIdx.x] + part[3][threadIdx.x];
        pbuf[blockIdx.x * 6 + threadIdx.x] = s;
    }
}

__global__ void enc_reduce_stage2(const float* __restrict__ pbuf, float* __restrict__ est) {
    int lane = threadIdx.x;
    float s[6] = {};
    for (int b = lane; b < ERB; b += 64)
#pragma unroll
        for (int j = 0; j < 6; ++j) s[j] += pbuf[b * 6 + j];
#pragma unroll
    for (int j = 0; j < 6; ++j) {
        float v = wave_sum(s[j]);
        if (lane == 0) est[j] = v;
    }
    __syncthreads();
    if (lane < 3) {
        float cnt = (float)NN * 128.f;
        float mean = est[2 * lane] / cnt;
        float var = est[2 * lane + 1] / cnt - mean * mean;
        var = fmaxf(var, 0.f);
        est[6 + 2 * lane] = mean;
        est[7 + 2 * lane] = 1.f / (sqrtf(var) + 1e-5f);
    }
}

__global__ __launch_bounds__(256) void enc_apply(
    unsigned short* __restrict__ hb, const float* __restrict__ est,
    const float* __restrict__ lw0, const float* __restrict__ lb0,
    const float* __restrict__ lw1, const float* __restrict__ lb1,
    const float* __restrict__ lw2, const float* __restrict__ lb2)
{
    long gt = (long)blockIdx.x * 256 + threadIdx.x;
    if (gt >= (long)NN * FF) return;
    int f = (int)(gt % FF);
    int enc = f >> 7, j = f & 127;
    const float* lw = enc == 0 ? lw0 : (enc == 1 ? lw1 : lw2);
    const float* lb = enc == 0 ? lb0 : (enc == 1 ? lb1 : lb2);
    float mean = est[6 + 2 * enc], sc = est[7 + 2 * enc];
    float v = (bflo((unsigned)hb[gt]) - mean) * sc * lw[j] + lb[j];
    hb[gt] = f2bf(v);
}

// ================= qkbuf via MFMA: [N,384] @ [384,48] from h directly =================
__global__ __launch_bounds__(256) void qk48_mfma(
    const unsigned short* __restrict__ hb,
    const unsigned short* __restrict__ wqkt,
    float* __restrict__ qkbuf)
{
    __shared__ __align__(16) unsigned short wlds[48 * 392];
    int t = threadIdx.x;
    for (int idx = t; idx < 48 * 192; idx += 256) {
        int row = idx / 192, dw = idx - row * 192;
        *((unsigned*)(wlds + row * 392) + dw) = ((const unsigned*)wqkt)[row * 192 + dw];
    }
    __syncthreads();
    int lane = t & 63, wid = t >> 6;
    int col = lane & 15, kq = lane >> 4;
    int tile = blockIdx.x * 4 + wid;
    const unsigned short* arow = hb + (size_t)(tile * 16 + col) * FF + kq * 8;
    f32x4 acc0 = {}, acc1 = {}, acc2 = {};
#pragma unroll
    for (int kt = 0; kt < 12; ++kt) {
        bf16x8 af = *(const bf16x8*)(arow + kt * 32);
        bf16x8 b0 = *(const bf16x8*)(wlds + (0 * 16 + col) * 392 + kt * 32 + kq * 8);
        bf16x8 b1 = *(const bf16x8*)(wlds + (1 * 16 + col) * 392 + kt * 32 + kq * 8);
        bf16x8 b2 = *(const bf16x8*)(wlds + (2 * 16 + col) * 392 + kt * 32 + kq * 8);
        acc0 = __builtin_amdgcn_mfma_f32_16x16x32_bf16(af, b0, acc0, 0, 0, 0);
        acc1 = __builtin_amdgcn_mfma_f32_16x16x32_bf16(af, b1, acc1, 0, 0, 0);
        acc2 = __builtin_amdgcn_mfma_f32_16x16x32_bf16(af, b2, acc2, 0, 0, 0);
    }
    int row0 = kq << 2;
#pragma unroll
    for (int j = 0; j < 4; ++j) {
        size_t node = (size_t)tile * 16 + row0 + j;
        qkbuf[node * 48 + 0 + col]  = acc0[j];
        qkbuf[node * 48 + 16 + col] = acc1[j];
        qkbuf[node * 48 + 32 + col] = acc2[j];
    }
}

// ================= single-pass softmax + gather + elu + residual + stats =================
// elist loaded 64-wide once per chunk; __shfl(.., e) with uniform e -> v_readlane
// -> et/src scalar -> xt row loads have no per-edge memory dependency.
__global__ __launch_bounds__(256) void gather_fused(
    const int* __restrict__ rps, const int* __restrict__ deg, const int* __restrict__ elist,
    const float* __restrict__ qkbuf, const unsigned short* __restrict__ xt,
    const unsigned short* __restrict__ hbin, const float* __restrict__ rb, const int* __restrict__ batch,
    float* __restrict__ gs1, float* __restrict__ gs2, unsigned short* __restrict__ ybuf)
{
    int node = blockIdx.x * 4 + (threadIdx.x >> 6);
    int lane = threadIdx.x & 63;
    int d = deg[node], rp = rps[node];
    int head = lane >> 3;
    float qd0 = qkbuf[(size_t)node * 48 + 0 + head];
    float qd1 = qkbuf[(size_t)node * 48 + 16 + head];
    float qd2 = qkbuf[(size_t)node * 48 + 32 + head];
    // residual row (independent; issue early)
    const unsigned* hr = (const unsigned*)(hbin + (size_t)node * FF) + lane * 3;
    unsigned h0u = hr[0], h1u = hr[1], h2u = hr[2];
    float s = 0.f;
    float acc0 = 0.f, acc1 = 0.f, acc2 = 0.f, acc3 = 0.f, acc4 = 0.f, acc5 = 0.f;
    for (int base = 0; base < d; base += 64) {
        int myp = (base + lane < d) ? elist[rp + base + lane] : 0;
        int lim = d - base; if (lim > 64) lim = 64;
        for (int e = 0; e < lim; ++e) {
            int packed = __shfl(myp, e);            // uniform idx -> readlane -> scalar
            int et = packed >> 16, src = packed & 0xFFFF;
            const unsigned* xr = (const unsigned*)(xt + ((size_t)et * NN + src) * FF) + lane * 3;
            unsigned u0 = xr[0], u1 = xr[1], u2 = xr[2];
            float qd = et == 0 ? qd0 : (et == 1 ? qd1 : qd2);
            float a = qd + qkbuf[(size_t)src * 48 + et * 16 + 8 + head];
            a = a >= 0.f ? a : NEG_SLOPE * a;
            float pw = __expf(a);   // alpha bounded => safe without max shift
            s += pw;
            acc0 = fmaf(pw, bflo(u0), acc0); acc1 = fmaf(pw, bfhi(u0), acc1);
            acc2 = fmaf(pw, bflo(u1), acc2); acc3 = fmaf(pw, bfhi(u1), acc3);
            acc4 = fmaf(pw, bflo(u2), acc4); acc5 = fmaf(pw, bfhi(u2), acc5);
        }
    }
    float inv = 1.f / (s + 1e-16f);
    float hv[6] = {bflo(h0u), bfhi(h0u), bflo(h1u), bfhi(h1u), bflo(h2u), bfhi(h2u)};
    float av[6] = {acc0, acc1, acc2, acc3, acc4, acc5};
    int f0 = lane * 6;
    float s1 = 0.f, s2 = 0.f;
    float yv[6];
#pragma unroll
    for (int i = 0; i < 6; ++i) {
        float mv = av[i] * inv + rb[f0 + i];
        float e = mv > 0.f ? mv : (__expf(mv) - 1.f);
        float y = hv[i] + e;
        yv[i] = y;
        s1 += y; s2 += y * y;
    }
    unsigned* yrow = (unsigned*)(ybuf + (size_t)node * FF) + lane * 3;
    yrow[0] = pk2(yv[0], yv[1]);
    yrow[1] = pk2(yv[2], yv[3]);
    yrow[2] = pk2(yv[4], yv[5]);
    s1 = wave_sum(s1);
    s2 = wave_sum(s2);
    if (lane == 0) {
        int g = batch[node];
        atomicAdd(&gs1[g], s1);
        atomicAdd(&gs2[g], s2);
    }
}

// ================= LN apply with inline per-graph finalize =================
__global__ __launch_bounds__(256) void ln_apply(
    const unsigned short* __restrict__ y, const int* __restrict__ batch,
    const float* __restrict__ gcnt, const float* __restrict__ gs1, const float* __restrict__ gs2,
    const float* __restrict__ w, const float* __restrict__ b,
    unsigned short* __restrict__ hbOut)
{
    long gt = (long)blockIdx.x * 256 + threadIdx.x;
    int n = (int)(gt >> 6);
    if (n >= NN) return;
    int lane = (int)(gt & 63);
    int f0 = lane * 6;
    int g = batch[n];
    float cnt = fmaxf(gcnt[g], 1.f) * (float)FF;
    float mean = gs1[g] / cnt;
    float var = fmaxf(gs2[g] / cnt - mean * mean, 0.f);
    float rs = 1.f / sqrtf(var + 1e-5f);
    const unsigned* yr = (const unsigned*)(y + (size_t)n * FF) + lane * 3;
    unsigned u0 = yr[0], u1 = yr[1], u2 = yr[2];
    float yv[6] = {bflo(u0), bfhi(u0), bflo(u1), bfhi(u1), bflo(u2), bfhi(u2)};
    float ov[6];
#pragma unroll
    for (int i = 0; i < 6; ++i)
        ov[i] = (yv[i] - mean) * rs * w[f0 + i] + b[f0 + i];
    unsigned* orow = (unsigned*)(hbOut + (size_t)n * FF) + lane * 3;
    orow[0] = pk2(ov[0], ov[1]);
    orow[1] = pk2(ov[2], ov[3]);
    orow[2] = pk2(ov[4], ov[5]);
}

// ================= host-side layer driver =================
static void rgat_layer(hipStream_t stream,
    const unsigned short* hbIn,
    const float* rb, const float* lnw, const float* lnb,
    const int* rps, const int* deg, const int* elist, const int* batch,
    const unsigned short* wt, unsigned short* xt, const unsigned short* wqkt, float* qkbuf,
    float* gs, const float* gcnt,
    unsigned short* ybuf, unsigned short* hbOut)
{
    gemm_mfma<0, true, true><<<dim3(384, 3, 3), 256, 0, stream>>>(
        hbIn, FF, wt, nullptr, xt, FF, (size_t)FF * FF, (size_t)NN * FF);
    qk48_mfma<<<NN / 64, 256, 0, stream>>>(hbIn, wqkt, qkbuf);
    gather_fused<<<NN / 4, 256, 0, stream>>>(rps, deg, elist, qkbuf, xt, hbIn, rb, batch,
                                             gs, gs + GG, ybuf);
    ln_apply<<<NN / 4, 256, 0, stream>>>(ybuf, batch, gcnt, gs, gs + GG, lnw, lnb, hbOut);
}

extern "C" void kernel_launch(void* const* d_in, const int* in_sizes, int n_in,
                              void* d_out, int out_size, void* d_ws, size_t ws_size,
                              hipStream_t stream)
{
    const float* x_visual = (const float*)d_in[0];
    const float* x_geom   = (const float*)d_in[1];
    const float* x_prior  = (const float*)d_in[2];
    const float* vis_w  = (const float*)d_in[3];
    const float* vis_b  = (const float*)d_in[4];
    const float* vis_lw = (const float*)d_in[5];
    const float* vis_lb = (const float*)d_in[6];
    const float* geom_w  = (const float*)d_in[7];
    const float* geom_b  = (const float*)d_in[8];
    const float* geom_lw = (const float*)d_in[9];
    const float* geom_lb = (const float*)d_in[10];
    const float* prior_w  = (const float*)d_in[11];
    const float* prior_b  = (const float*)d_in[12];
    const float* prior_lw = (const float*)d_in[13];
    const float* prior_lb = (const float*)d_in[14];
    const float* r1_w = (const float*)d_in[15];
    const float* r1_q = (const float*)d_in[16];
    const float* r1_k = (const float*)d_in[17];
    const float* r1_b = (const float*)d_in[18];
    const float* n1_w = (const float*)d_in[19];
    const float* n1_b = (const float*)d_in[20];
    const float* r2_w = (const float*)d_in[21];
    const float* r2_q = (const float*)d_in[22];
    const float* r2_k = (const float*)d_in[23];
    const float* r2_b = (const float*)d_in[24];
    const float* n2_w = (const float*)d_in[25];
    const float* n2_b = (const float*)d_in[26];
    const float* c_w1 = (const float*)d_in[27];
    const float* c_b1 = (const float*)d_in[28];
    const float* c_w2 = (const float*)d_in[29];
    const float* c_b2 = (const float*)d_in[30];
    const int* ei_o  = (const int*)d_in[31];
    const int* ei_a  = (const int*)d_in[32];
    const int* ei_s  = (const int*)d_in[33];
    const int* batch = (const int*)d_in[34];
    float* out = (float*)d_out;

    char* p = (char*)d_ws;
    auto alloc = [&](size_t bytes) { char* r = p; p += (bytes + 255) & ~(size_t)255; return r; };
    unsigned short* hbA = (unsigned short*)alloc((size_t)NN * FF * 2);
    unsigned short* hbB = (unsigned short*)alloc((size_t)NN * FF * 2);
    unsigned short* ybuf = (unsigned short*)alloc((size_t)NN * FF * 2);
    unsigned short* xt = (unsigned short*)alloc((size_t)3 * NN * FF * 2);
    unsigned short* wt1 = (unsigned short*)alloc((size_t)3 * FF * FF * 2);
    unsigned short* wt2 = (unsigned short*)alloc((size_t)3 * FF * FF * 2);
    unsigned short* wtv = (unsigned short*)alloc((size_t)1024 * 128 * 2);
    unsigned short* wtc = (unsigned short*)alloc((size_t)FF * 128 * 2);
    float* qkbuf = (float*)alloc((size_t)NN * 48 * 4);
    unsigned short* wqkt1 = (unsigned short*)alloc((size_t)48 * FF * 2);
    unsigned short* wqkt2 = (unsigned short*)alloc((size_t)48 * FF * 2);
    float* t128 = (float*)alloc((size_t)NN * 128 * 4);
    int* rps = (int*)alloc(NN * 4);
    int* elist = (int*)alloc(ETOT * 4);
    float* est = (float*)alloc(64);
    float* pbuf = (float*)alloc(ERB * 6 * 4);
    // ---- contiguous zero-init region (one memset) ----
    char* z0 = alloc((size_t)2 * NN * 4 + 256 + (size_t)4 * GG * 4 + GG * 4);
    int* deg = (int*)z0;
    int* fill = deg + NN;
    int* counter = (int*)(z0 + (size_t)2 * NN * 4);
    float* gs = (float*)(z0 + (size_t)2 * NN * 4 + 256);        // 4*GG: layer1 s1,s2 | layer2 s1,s2
    float* gcnt = gs + 4 * GG;
    hipMemsetAsync(z0, 0, (size_t)2 * NN * 4 + 256 + (size_t)4 * GG * 4 + GG * 4, stream);

    // ---- CSR build + per-graph node counts ----
    csr_count<<<ETOT / 256, 256, 0, stream>>>(ei_o, ei_a, ei_s, deg);
    csr_alloc<<<NN / 256, 256, 0, stream>>>(deg, counter, rps, batch, gcnt);
    csr_fill<<<ETOT / 256, 256, 0, stream>>>(ei_o, ei_a, ei_s, rps, fill, elist);

    // ---- all weight prep up front ----
    transpose2_bf<<<(6 * FF * FF + 255) / 256, 256, 0, stream>>>(r1_w, r2_w, wt1, wt2);
    wqk_prep2<<<dim3(3, 6, 2), 256, 0, stream>>>(r1_w, r1_q, r1_k, r2_w, r2_q, r2_k, wqkt1, wqkt2);
    transpose_bf<<<(1024 * 128 + 255) / 256, 256, 0, stream>>>(vis_w, wtv, 1024, 128, 1024 * 128);
    transpose_bf<<<(FF * 128 + 255) / 256, 256, 0, stream>>>(c_w1, wtc, FF, 128, FF * 128);

    // ---- encoders (all-bf16 h) ----
    gemm_mfma<1, false, true><<<dim3(384, 1, 1), 256, 0, stream>>>(
        x_visual, 1024, wtv, vis_b, hbA, FF, 0, 0);
    gemm_k<1, true><<<dim3(2, 768, 1), 256, 0, stream>>>(x_geom, 6, geom_w, 128, geom_b, hbA + 128, FF, 128);
    gemm_k<1, true><<<dim3(2, 768, 1), 256, 0, stream>>>(x_prior, 50, prior_w, 128, prior_b, hbA + 256, FF, 128);
    enc_reduce_stage1<<<ERB, 256, 0, stream>>>(hbA, pbuf);
    enc_reduce_stage2<<<1, 64, 0, stream>>>(pbuf, est);
    enc_apply<<<(int)((size_t)NN * FF / 256), 256, 0, stream>>>(
        hbA, est, vis_lw, vis_lb, geom_lw, geom_lb, prior_lw, prior_lb);

    // ---- RGAT layers (bf16 ping-pong hbA -> hbB -> hbA) ----
    rgat_layer(stream, hbA, r1_b, n1_w, n1_b, rps, deg, elist, batch,
               wt1, xt, wqkt1, qkbuf, gs, gcnt, ybuf, hbB);
    rgat_layer(stream, hbB, r2_b, n2_w, n2_b, rps, deg, elist, batch,
               wt2, xt, wqkt2, qkbuf, gs + 2 * GG, gcnt, ybuf, hbA);

    // ---- classifier ----
    gemm_mfma<1, true, false><<<dim3(384, 1, 1), 256, 0, stream>>>(
        hbA, FF, wtc, c_b1, t128, 128, 0, 0);
    gemm_k<0, false><<<dim3(1, 768, 1), 256, 0, stream>>>(t128, 128, c_w2, 49, c_b2, out, 49, 49);
}

// Round 12
// 678.713 us; speedup vs baseline: 1.4320x; 1.0322x over previous
//
#include <hip/hip_runtime.h>
#include <hip/hip_bf16.h>

#define NN 49152
#define GG 1024
#define EE 65536
#define ETOT 196608
#define FF 384
#define NEG_SLOPE 0.2f

typedef __attribute__((ext_vector_type(8))) short bf16x8;
typedef __attribute__((ext_vector_type(4))) float f32x4;

__device__ __forceinline__ float wave_sum(float v) {
#pragma unroll
    for (int m = 32; m; m >>= 1) v += __shfl_xor(v, m);
    return v;
}
__device__ __forceinline__ unsigned short f2bf(float f) {
    __hip_bfloat16 b = __float2bfloat16(f);
    return *reinterpret_cast<unsigned short*>(&b);
}
__device__ __forceinline__ float bflo(unsigned u) { return __uint_as_float(u << 16); }
__device__ __forceinline__ float bfhi(unsigned u) { return __uint_as_float(u & 0xffff0000u); }
__device__ __forceinline__ unsigned pk2(float lo, float hi) {
    return ((unsigned)f2bf(hi) << 16) | (unsigned)f2bf(lo);
}

__device__ __forceinline__ void gload_lds16(const void* g, void* l) {
    __builtin_amdgcn_global_load_lds(
        (const __attribute__((address_space(1))) unsigned int*)g,
        (__attribute__((address_space(3))) unsigned int*)l, 16, 0, 0);
}

// ================= MFMA bf16 GEMM: C = act(A @ Bt^T + bias) =================
// Grid: x = M-tiles, y = N-tiles, z = batch (A-tile sharers land on one XCD).
__device__ __forceinline__ int swz(int row, int c16) {
    return row * 64 + ((c16 ^ ((row >> 1) & 3)) << 4);
}

template <int ACT, bool ABF, bool OBF>
__global__ __launch_bounds__(256) void gemm_mfma(
    const void* __restrict__ Ag, int K,
    const unsigned short* __restrict__ Btg,
    const float* __restrict__ bias,
    void* __restrict__ Cg, int ldc,
    size_t bzs, size_t czs)
{
    __shared__ __align__(16) char As[8192];
    __shared__ __align__(16) char Bs[8192];
    const unsigned short* Bt = Btg + (size_t)blockIdx.z * bzs;
    int t = threadIdx.x;
    int bm = blockIdx.x << 7, bn = blockIdx.y << 7;
    int lane = t & 63, wid = t >> 6, wr = wid >> 1, wc = wid & 1;
    f32x4 acc[4][4] = {};
    int ktn = K >> 5;
    for (int kt = 0; kt < ktn; ++kt) {
        int k0 = kt << 5;
#pragma unroll
        for (int ii = 0; ii < 2; ++ii) {
            int id = t + (ii << 8);
            int row = id >> 2, c = id & 3;
            int csrc = c ^ ((row >> 1) & 3);
            size_t ldsoff = (size_t)((wid << 10) + (ii << 12));
            if (ABF) {
                const unsigned short* srcA = (const unsigned short*)Ag + (size_t)(bm + row) * K + k0 + csrc * 8;
                gload_lds16(srcA, As + ldsoff);
            } else {
                const float* srcA = (const float*)Ag + (size_t)(bm + row) * K + k0 + c * 8;
                float4 a0 = *(const float4*)srcA;
                float4 a1 = *(const float4*)(srcA + 4);
                union { unsigned short u[8]; int4 v; } P;
                P.u[0] = f2bf(a0.x); P.u[1] = f2bf(a0.y); P.u[2] = f2bf(a0.z); P.u[3] = f2bf(a0.w);
                P.u[4] = f2bf(a1.x); P.u[5] = f2bf(a1.y); P.u[6] = f2bf(a1.z); P.u[7] = f2bf(a1.w);
                *(int4*)(As + swz(row, c)) = P.v;
            }
            const unsigned short* srcB = Bt + (size_t)(bn + row) * K + k0 + csrc * 8;
            gload_lds16(srcB, Bs + ldsoff);
        }
        __syncthreads();
        int c16 = lane >> 4;
        bf16x8 af[4], bfr[4];
#pragma unroll
        for (int m = 0; m < 4; ++m)
            af[m] = *(const bf16x8*)(As + swz((wr << 6) + (m << 4) + (lane & 15), c16));
#pragma unroll
        for (int n = 0; n < 4; ++n)
            bfr[n] = *(const bf16x8*)(Bs + swz((wc << 6) + (n << 4) + (lane & 15), c16));
#pragma unroll
        for (int m = 0; m < 4; ++m)
#pragma unroll
            for (int n = 0; n < 4; ++n)
                acc[m][n] = __builtin_amdgcn_mfma_f32_16x16x32_bf16(af[m], bfr[n], acc[m][n], 0, 0, 0);
        __syncthreads();
    }
#pragma unroll
    for (int m = 0; m < 4; ++m) {
#pragma unroll
        for (int n = 0; n < 4; ++n) {
            int row0 = bm + (wr << 6) + (m << 4) + ((lane >> 4) << 2);
            int col = bn + (wc << 6) + (n << 4) + (lane & 15);
            float bv = bias ? bias[col] : 0.f;
#pragma unroll
            for (int j = 0; j < 4; ++j) {
                float v = acc[m][n][j] + bv;
                if (ACT == 1) v = fmaxf(v, 0.f);
                if (OBF) {
                    unsigned short* C = (unsigned short*)Cg + (size_t)blockIdx.z * czs;
                    C[(size_t)(row0 + j) * ldc + col] = f2bf(v);
                } else {
                    float* C = (float*)Cg + (size_t)blockIdx.z * czs;
                    C[(size_t)(row0 + j) * ldc + col] = v;
                }
            }
        }
    }
}

// ================= f32-input fallback GEMM (small K / small N), optional bf16 out =================
template <int ACT, bool OBF>
__global__ __launch_bounds__(256) void gemm_k(
    const float* __restrict__ A, int K,
    const float* __restrict__ W, int Jw,
    const float* __restrict__ bias,
    void* __restrict__ Cg, int ldc, int jmax)
{
    __shared__ float Ash[16][64];
    __shared__ float Bsh[16][68];
    int tid = threadIdx.x;
    int bj = blockIdx.x << 6;
    int bm = blockIdx.y << 6;
    int tx = tid & 15, ty = tid >> 4;
    float acc[4][4] = {};
    int ktn = (K + 15) >> 4;
    int ar = tid >> 2;
    int aks = (tid & 3) << 2;
    int wk = tid >> 4;
    int wjs = (tid & 15) << 2;
    for (int kt = 0; kt < ktn; ++kt) {
        int k0 = kt << 4;
        const float* Ap = A + (size_t)(bm + ar) * K + k0 + aks;
#pragma unroll
        for (int i = 0; i < 4; ++i) {
            int k = k0 + aks + i;
            Ash[aks + i][ar] = (k < K) ? Ap[i] : 0.f;
        }
        const float* Wp = W + (size_t)(k0 + wk) * Jw + bj + wjs;
        bool kok = (k0 + wk) < K;
#pragma unroll
        for (int i = 0; i < 4; ++i) {
            int j = bj + wjs + i;
            Bsh[wk][wjs + i] = (kok && j < jmax) ? Wp[i] : 0.f;
        }
        __syncthreads();
#pragma unroll
        for (int kk = 0; kk < 16; ++kk) {
            const float4 av = *reinterpret_cast<const float4*>(&Ash[kk][ty << 2]);
            const float4 bv = *reinterpret_cast<const float4*>(&Bsh[kk][tx << 2]);
            float aa[4] = {av.x, av.y, av.z, av.w};
            float bb[4] = {bv.x, bv.y, bv.z, bv.w};
#pragma unroll
            for (int i = 0; i < 4; ++i)
#pragma unroll
                for (int j = 0; j < 4; ++j)
                    acc[i][j] = fmaf(aa[i], bb[j], acc[i][j]);
        }
        __syncthreads();
    }
#pragma unroll
    for (int i = 0; i < 4; ++i) {
        int row = bm + (ty << 2) + i;
#pragma unroll
        for (int j = 0; j < 4; ++j) {
            int col = bj + (tx << 2) + j;
            if (col < jmax) {
                float v = acc[i][j];
                if (bias) v += bias[col];
                if (ACT == 1) v = fmaxf(v, 0.f);
                if (OBF) ((unsigned short*)Cg)[(size_t)row * ldc + col] = f2bf(v);
                else     ((float*)Cg)[(size_t)row * ldc + col] = v;
            }
        }
    }
}

// fused geom+prior encoder GEMM: z selects input set; bf16 out with relu
__global__ __launch_bounds__(256) void gemm_k2_enc(
    const float* __restrict__ A0, const float* __restrict__ W0, const float* __restrict__ b0,
    const float* __restrict__ A1, const float* __restrict__ W1, const float* __restrict__ b1,
    unsigned short* __restrict__ hb)
{
    __shared__ float Ash[16][64];
    __shared__ float Bsh[16][68];
    int z = blockIdx.z;
    const float* A = z ? A1 : A0;
    const float* W = z ? W1 : W0;
    const float* bias = z ? b1 : b0;
    int K = z ? 50 : 6;
    int colbase = z ? 256 : 128;
    int tid = threadIdx.x;
    int bj = blockIdx.x << 6;
    int bm = blockIdx.y << 6;
    int tx = tid & 15, ty = tid >> 4;
    float acc[4][4] = {};
    int ktn = (K + 15) >> 4;
    int ar = tid >> 2;
    int aks = (tid & 3) << 2;
    int wk = tid >> 4;
    int wjs = (tid & 15) << 2;
    for (int kt = 0; kt < ktn; ++kt) {
        int k0 = kt << 4;
        const float* Ap = A + (size_t)(bm + ar) * K + k0 + aks;
#pragma unroll
        for (int i = 0; i < 4; ++i) {
            int k = k0 + aks + i;
            Ash[aks + i][ar] = (k < K) ? Ap[i] : 0.f;
        }
        const float* Wp = W + (size_t)(k0 + wk) * 128 + bj + wjs;
        bool kok = (k0 + wk) < K;
#pragma unroll
        for (int i = 0; i < 4; ++i)
            Bsh[wk][wjs + i] = kok ? Wp[i] : 0.f;
        __syncthreads();
#pragma unroll
        for (int kk = 0; kk < 16; ++kk) {
            const float4 av = *reinterpret_cast<const float4*>(&Ash[kk][ty << 2]);
            const float4 bv = *reinterpret_cast<const float4*>(&Bsh[kk][tx << 2]);
            float aa[4] = {av.x, av.y, av.z, av.w};
            float bb[4] = {bv.x, bv.y, bv.z, bv.w};
#pragma unroll
            for (int i = 0; i < 4; ++i)
#pragma unroll
                for (int j = 0; j < 4; ++j)
                    acc[i][j] = fmaf(aa[i], bb[j], acc[i][j]);
        }
        __syncthreads();
    }
#pragma unroll
    for (int i = 0; i < 4; ++i) {
        int row = bm + (ty << 2) + i;
#pragma unroll
        for (int j = 0; j < 4; ++j) {
            int col = bj + (tx << 2) + j;
            float v = fmaxf(acc[i][j] + bias[col], 0.f);
            hb[(size_t)row * FF + colbase + col] = f2bf(v);
        }
    }
}

// ================= generic weight transpose + bf16 convert: Wt[z][n][k] = W[z][k][n] =================
__global__ void transpose_bf(const float* __restrict__ W, unsigned short* __restrict__ Wt,
                             int K, int N, int total) {
    int i = blockIdx.x * 256 + threadIdx.x;
    if (i >= total) return;
    int kn = K * N;
    int z = i / kn, rem = i - z * kn;
    int k = rem / N, n = rem - k * N;
    Wt[(size_t)z * kn + (size_t)n * K + k] = f2bf(W[i]);
}

// both layers' relation weights in one launch: 6 z-slices of [384][384]
__global__ void transpose2_bf(const float* __restrict__ W1, const float* __restrict__ W2,
                              unsigned short* __restrict__ Wt1, unsigned short* __restrict__ Wt2) {
    int i = blockIdx.x * 256 + threadIdx.x;
    if (i >= 6 * FF * FF) return;
    int z = i / (FF * FF), rem = i - z * (FF * FF);
    int k = rem / FF, n = rem - k * FF;
    const float* W = (z < 3) ? W1 + (size_t)z * FF * FF : W2 + (size_t)(z - 3) * FF * FF;
    unsigned short* Wt = (z < 3) ? Wt1 + (size_t)z * FF * FF : Wt2 + (size_t)(z - 3) * FF * FF;
    Wt[(size_t)n * FF + k] = f2bf(W[(size_t)k * FF + n]);
}

// ================= wqkt[r*16 + qk*8 + h][f] = sum_c rw[r][f][c] * (qk?k:q)[c][h] =================
__global__ __launch_bounds__(256) void wqk_prep2(
    const float* __restrict__ rw1, const float* __restrict__ q1, const float* __restrict__ k1,
    const float* __restrict__ rw2, const float* __restrict__ q2, const float* __restrict__ k2,
    unsigned short* __restrict__ wqkt1, unsigned short* __restrict__ wqkt2)
{
    __shared__ float qsT[16 * 384];
    int t = threadIdx.x;
    int r = blockIdx.x, ftile = blockIdx.y, layer = blockIdx.z;
    const float* rw = layer ? rw2 : rw1;
    const float* q = layer ? q2 : q1;
    const float* k = layer ? k2 : k1;
    unsigned short* wqkt = layer ? wqkt2 : wqkt1;
    for (int idx = t; idx < 384 * 16; idx += 256) {
        int c = idx >> 4, j = idx & 15;
        qsT[j * 384 + c] = (j < 8) ? q[c * 8 + j] : k[c * 8 + j - 8];
    }
    __syncthreads();
    int j = t & 15, fi = t >> 4;
    const float4* q4 = (const float4*)(qsT + j * 384);
#pragma unroll
    for (int rr = 0; rr < 4; ++rr) {
        int f = ftile * 64 + fi * 4 + rr;
        const float4* a4 = (const float4*)(rw + (size_t)r * FF * FF + (size_t)f * FF);
        float dot = 0.f;
        for (int c4 = 0; c4 < 96; ++c4) {
            float4 a = a4[c4], b = q4[c4];
            dot += a.x * b.x + a.y * b.y + a.z * b.z + a.w * b.w;
        }
        wqkt[(size_t)(r * 16 + j) * FF + f] = f2bf(dot);
    }
}

// ================= CSR build =================
__global__ void csr_count(const int* __restrict__ eo, const int* __restrict__ ea,
                          const int* __restrict__ es, int* __restrict__ deg) {
    int e = blockIdx.x * 256 + threadIdx.x;
    if (e >= ETOT) return;
    int et = e >> 16, le = e & 65535;
    const int* ei = et == 0 ? eo : (et == 1 ? ea : es);
    atomicAdd(&deg[ei[EE + le]], 1);
}
__global__ void csr_alloc(const int* __restrict__ deg, int* __restrict__ counter,
                          int* __restrict__ rps, const int* __restrict__ batch,
                          float* __restrict__ gcnt) {
    int n = blockIdx.x * 256 + threadIdx.x;
    int lane = threadIdx.x & 63;
    int d = (n < NN) ? deg[n] : 0;
    int x = d;
#pragma unroll
    for (int off = 1; off < 64; off <<= 1) {
        int y = __shfl_up(x, off);
        if (lane >= off) x += y;
    }
    int total = __shfl(x, 63);
    int base = 0;
    if (lane == 63) base = atomicAdd(counter, total);
    base = __shfl(base, 63);
    if (n < NN) {
        rps[n] = base + x - d;
        atomicAdd(&gcnt[batch[n]], 1.f);
    }
}
__global__ void csr_fill(const int* __restrict__ eo, const int* __restrict__ ea,
                         const int* __restrict__ es, const int* __restrict__ rps,
                         int* __restrict__ fill, int* __restrict__ elist) {
    int e = blockIdx.x * 256 + threadIdx.x;
    if (e >= ETOT) return;
    int et = e >> 16, le = e & 65535;
    const int* ei = et == 0 ? eo : (et == 1 ? ea : es);
    int src = ei[le], dst = ei[EE + le];
    int pos = rps[dst] + atomicAdd(&fill[dst], 1);
    elist[pos] = (et << 16) | src;
}

// ================= encoder stats over bf16 h: two-stage, no atomics =================
#define ERB 512
__global__ __launch_bounds__(256) void enc_reduce_stage1(const unsigned short* __restrict__ hb, float* __restrict__ pbuf) {
    __shared__ float part[4][6];
    float a1 = 0.f, a2 = 0.f, b1 = 0.f, b2 = 0.f, c1 = 0.f, c2 = 0.f;
    const uint4* h8 = (const uint4*)hb;
    int total8 = NN * FF / 8;
    for (int i = blockIdx.x * 256 + threadIdx.x; i < total8; i += ERB * 256) {
        uint4 v = h8[i];
        float e0 = bflo(v.x), e1 = bfhi(v.x), e2 = bflo(v.y), e3 = bfhi(v.y);
        float e4 = bflo(v.z), e5 = bfhi(v.z), e6 = bflo(v.w), e7 = bfhi(v.w);
        float s1 = e0 + e1 + e2 + e3 + e4 + e5 + e6 + e7;
        float s2 = e0*e0 + e1*e1 + e2*e2 + e3*e3 + e4*e4 + e5*e5 + e6*e6 + e7*e7;
        int enc = (i % 48) >> 4;
        if (enc == 0)      { a1 += s1; a2 += s2; }
        else if (enc == 1) { b1 += s1; b2 += s2; }
        else               { c1 += s1; c2 += s2; }
    }
    a1 = wave_sum(a1); a2 = wave_sum(a2);
    b1 = wave_sum(b1); b2 = wave_sum(b2);
    c1 = wave_sum(c1); c2 = wave_sum(c2);
    int w = threadIdx.x >> 6;
    if ((threadIdx.x & 63) == 0) {
        part[w][0] = a1; part[w][1] = a2; part[w][2] = b1;
        part[w][3] = b2; part[w][4] = c1; part[w][5] = c2;
    }
    __syncthreads();
    if (threadIdx.x < 6) {
        float s = part[0][threadIdx.x] + part[1][threadIdx.x] + part[2][threadIdx.x] + part[3][threadIdx.x];
        pbuf[blockIdx.x * 6 + threadIdx.x] = s;
    }
}

__global__ void enc_reduce_stage2(const float* __restrict__ pbuf, float* __restrict__ est) {
    int lane = threadIdx.x;
    float s[6] = {};
    for (int b = lane; b < ERB; b += 64)
#pragma unroll
        for (int j = 0; j < 6; ++j) s[j] += pbuf[b * 6 + j];
#pragma unroll
    for (int j = 0; j < 6; ++j) {
        float v = wave_sum(s[j]);
        if (lane == 0) est[j] = v;
    }
    __syncthreads();
    if (lane < 3) {
        float cnt = (float)NN * 128.f;
        float mean = est[2 * lane] / cnt;
        float var = est[2 * lane + 1] / cnt - mean * mean;
        var = fmaxf(var, 0.f);
        est[6 + 2 * lane] = mean;
        est[7 + 2 * lane] = 1.f / (sqrtf(var) + 1e-5f);
    }
}

__global__ __launch_bounds__(256) void enc_apply(
    unsigned short* __restrict__ hb, const float* __restrict__ est,
    const float* __restrict__ lw0, const float* __restrict__ lb0,
    const float* __restrict__ lw1, const float* __restrict__ lb1,
    const float* __restrict__ lw2, const float* __restrict__ lb2)
{
    long gt = (long)blockIdx.x * 256 + threadIdx.x;
    if (gt >= (long)NN * FF) return;
    int f = (int)(gt % FF);
    int enc = f >> 7, j = f & 127;
    const float* lw = enc == 0 ? lw0 : (enc == 1 ? lw1 : lw2);
    const float* lb = enc == 0 ? lb0 : (enc == 1 ? lb1 : lb2);
    float mean = est[6 + 2 * enc], sc = est[7 + 2 * enc];
    float v = (bflo((unsigned)hb[gt]) - mean) * sc * lw[j] + lb[j];
    hb[gt] = f2bf(v);
}

// ================= qkbuf via MFMA: [N,384] @ [384,48] from h directly =================
__global__ __launch_bounds__(256) void qk48_mfma(
    const unsigned short* __restrict__ hb,
    const unsigned short* __restrict__ wqkt,
    float* __restrict__ qkbuf)
{
    __shared__ __align__(16) unsigned short wlds[48 * 392];
    int t = threadIdx.x;
    for (int idx = t; idx < 48 * 192; idx += 256) {
        int row = idx / 192, dw = idx - row * 192;
        *((unsigned*)(wlds + row * 392) + dw) = ((const unsigned*)wqkt)[row * 192 + dw];
    }
    __syncthreads();
    int lane = t & 63, wid = t >> 6;
    int col = lane & 15, kq = lane >> 4;
    int tile = blockIdx.x * 4 + wid;
    const unsigned short* arow = hb + (size_t)(tile * 16 + col) * FF + kq * 8;
    f32x4 acc0 = {}, acc1 = {}, acc2 = {};
#pragma unroll
    for (int kt = 0; kt < 12; ++kt) {
        bf16x8 af = *(const bf16x8*)(arow + kt * 32);
        bf16x8 b0 = *(const bf16x8*)(wlds + (0 * 16 + col) * 392 + kt * 32 + kq * 8);
        bf16x8 b1 = *(const bf16x8*)(wlds + (1 * 16 + col) * 392 + kt * 32 + kq * 8);
        bf16x8 b2 = *(const bf16x8*)(wlds + (2 * 16 + col) * 392 + kt * 32 + kq * 8);
        acc0 = __builtin_amdgcn_mfma_f32_16x16x32_bf16(af, b0, acc0, 0, 0, 0);
        acc1 = __builtin_amdgcn_mfma_f32_16x16x32_bf16(af, b1, acc1, 0, 0, 0);
        acc2 = __builtin_amdgcn_mfma_f32_16x16x32_bf16(af, b2, acc2, 0, 0, 0);
    }
    int row0 = kq << 2;
#pragma unroll
    for (int j = 0; j < 4; ++j) {
        size_t node = (size_t)tile * 16 + row0 + j;
        qkbuf[node * 48 + 0 + col]  = acc0[j];
        qkbuf[node * 48 + 16 + col] = acc1[j];
        qkbuf[node * 48 + 32 + col] = acc2[j];
    }
}

// ================= single-pass softmax + gather + elu + residual + stats =================
// 48 active lanes, 8 features (one dwordx4) each; lane's features never straddle a head
// (48 feat/head / 8 = 6 lanes per head). Lanes 48-63 only serve the elist chunk load.
__global__ __launch_bounds__(256) void gather_fused(
    const int* __restrict__ rps, const int* __restrict__ deg, const int* __restrict__ elist,
    const float* __restrict__ qkbuf, const unsigned short* __restrict__ xt,
    const unsigned short* __restrict__ hbin, const float* __restrict__ rb, const int* __restrict__ batch,
    float* __restrict__ gs1, float* __restrict__ gs2, unsigned short* __restrict__ ybuf)
{
    int node = blockIdx.x * 4 + (threadIdx.x >> 6);
    int lane = threadIdx.x & 63;
    bool act = lane < 48;
    int d = deg[node], rp = rps[node];
    int head = lane / 6; if (head > 7) head = 7;
    float qd0 = qkbuf[(size_t)node * 48 + 0 + head];
    float qd1 = qkbuf[(size_t)node * 48 + 16 + head];
    float qd2 = qkbuf[(size_t)node * 48 + 32 + head];
    // residual row (independent; issue early)
    uint4 hu = {0, 0, 0, 0};
    if (act) hu = *((const uint4*)(hbin + (size_t)node * FF) + lane);
    float s = 0.f;
    float a0 = 0.f, a1 = 0.f, a2 = 0.f, a3 = 0.f, a4 = 0.f, a5 = 0.f, a6 = 0.f, a7 = 0.f;
    for (int base = 0; base < d; base += 64) {
        int myp = (base + lane < d) ? elist[rp + base + lane] : 0;
        int lim = d - base; if (lim > 64) lim = 64;
        for (int e = 0; e < lim; ++e) {
            int packed = __shfl(myp, e);            // uniform idx -> readlane -> scalar
            int et = packed >> 16, src = packed & 0xFFFF;
            uint4 u = {0, 0, 0, 0};
            if (act) u = *((const uint4*)(xt + ((size_t)et * NN + src) * FF) + lane);
            float qd = et == 0 ? qd0 : (et == 1 ? qd1 : qd2);
            float a = qd + qkbuf[(size_t)src * 48 + et * 16 + 8 + head];
            a = a >= 0.f ? a : NEG_SLOPE * a;
            float pw = __expf(a);   // alpha bounded => safe without max shift
            s += pw;
            a0 = fmaf(pw, bflo(u.x), a0); a1 = fmaf(pw, bfhi(u.x), a1);
            a2 = fmaf(pw, bflo(u.y), a2); a3 = fmaf(pw, bfhi(u.y), a3);
            a4 = fmaf(pw, bflo(u.z), a4); a5 = fmaf(pw, bfhi(u.z), a5);
            a6 = fmaf(pw, bflo(u.w), a6); a7 = fmaf(pw, bfhi(u.w), a7);
        }
    }
    float inv = 1.f / (s + 1e-16f);
    float hv[8] = {bflo(hu.x), bfhi(hu.x), bflo(hu.y), bfhi(hu.y),
                   bflo(hu.z), bfhi(hu.z), bflo(hu.w), bfhi(hu.w)};
    float av[8] = {a0, a1, a2, a3, a4, a5, a6, a7};
    int f0 = lane * 8;
    float s1 = 0.f, s2 = 0.f;
    if (act) {
        float yv[8];
#pragma unroll
        for (int i = 0; i < 8; ++i) {
            float mv = av[i] * inv + rb[f0 + i];
            float e = mv > 0.f ? mv : (__expf(mv) - 1.f);
            float y = hv[i] + e;
            yv[i] = y;
            s1 += y; s2 += y * y;
        }
        uint4 pkv;
        pkv.x = pk2(yv[0], yv[1]); pkv.y = pk2(yv[2], yv[3]);
        pkv.z = pk2(yv[4], yv[5]); pkv.w = pk2(yv[6], yv[7]);
        *((uint4*)(ybuf + (size_t)node * FF) + lane) = pkv;
    }
    s1 = wave_sum(s1);
    s2 = wave_sum(s2);
    if (lane == 0) {
        int g = batch[node];
        atomicAdd(&gs1[g], s1);
        atomicAdd(&gs2[g], s2);
    }
}

// ================= LN apply with inline per-graph finalize =================
__global__ __launch_bounds__(256) void ln_apply(
    const unsigned short* __restrict__ y, const int* __restrict__ batch,
    const float* __restrict__ gcnt, const float* __restrict__ gs1, const float* __restrict__ gs2,
    const float* __restrict__ w, const float* __restrict__ b,
    unsigned short* __restrict__ hbOut)
{
    long gt = (long)blockIdx.x * 256 + threadIdx.x;
    int n = (int)(gt >> 6);
    if (n >= NN) return;
    int lane = (int)(gt & 63);
    int f0 = lane * 6;
    int g = batch[n];
    float cnt = fmaxf(gcnt[g], 1.f) * (float)FF;
    float mean = gs1[g] / cnt;
    float var = fmaxf(gs2[g] / cnt - mean * mean, 0.f);
    float rs = 1.f / sqrtf(var + 1e-5f);
    const unsigned* yr = (const unsigned*)(y + (size_t)n * FF) + lane * 3;
    unsigned u0 = yr[0], u1 = yr[1], u2 = yr[2];
    float yv[6] = {bflo(u0), bfhi(u0), bflo(u1), bfhi(u1), bflo(u2), bfhi(u2)};
    float ov[6];
#pragma unroll
    for (int i = 0; i < 6; ++i)
        ov[i] = (yv[i] - mean) * rs * w[f0 + i] + b[f0 + i];
    unsigned* orow = (unsigned*)(hbOut + (size_t)n * FF) + lane * 3;
    orow[0] = pk2(ov[0], ov[1]);
    orow[1] = pk2(ov[2], ov[3]);
    orow[2] = pk2(ov[4], ov[5]);
}

// ================= host-side layer driver =================
static void rgat_layer(hipStream_t stream,
    const unsigned short* hbIn,
    const float* rb, const float* lnw, const float* lnb,
    const int* rps, const int* deg, const int* elist, const int* batch,
    const unsigned short* wt, unsigned short* xt, const unsigned short* wqkt, float* qkbuf,
    float* gs, const float* gcnt,
    unsigned short* ybuf, unsigned short* hbOut)
{
    gemm_mfma<0, true, true><<<dim3(384, 3, 3), 256, 0, stream>>>(
        hbIn, FF, wt, nullptr, xt, FF, (size_t)FF * FF, (size_t)NN * FF);
    qk48_mfma<<<NN / 64, 256, 0, stream>>>(hbIn, wqkt, qkbuf);
    gather_fused<<<NN / 4, 256, 0, stream>>>(rps, deg, elist, qkbuf, xt, hbIn, rb, batch,
                                             gs, gs + GG, ybuf);
    ln_apply<<<NN / 4, 256, 0, stream>>>(ybuf, batch, gcnt, gs, gs + GG, lnw, lnb, hbOut);
}

extern "C" void kernel_launch(void* const* d_in, const int* in_sizes, int n_in,
                              void* d_out, int out_size, void* d_ws, size_t ws_size,
                              hipStream_t stream)
{
    const float* x_visual = (const float*)d_in[0];
    const float* x_geom   = (const float*)d_in[1];
    const float* x_prior  = (const float*)d_in[2];
    const float* vis_w  = (const float*)d_in[3];
    const float* vis_b  = (const float*)d_in[4];
    const float* vis_lw = (const float*)d_in[5];
    const float* vis_lb = (const float*)d_in[6];
    const float* geom_w  = (const float*)d_in[7];
    const float* geom_b  = (const float*)d_in[8];
    const float* geom_lw = (const float*)d_in[9];
    const float* geom_lb = (const float*)d_in[10];
    const float* prior_w  = (const float*)d_in[11];
    const float* prior_b  = (const float*)d_in[12];
    const float* prior_lw = (const float*)d_in[13];
    const float* prior_lb = (const float*)d_in[14];
    const float* r1_w = (const float*)d_in[15];
    const float* r1_q = (const float*)d_in[16];
    const float* r1_k = (const float*)d_in[17];
    const float* r1_b = (const float*)d_in[18];
    const float* n1_w = (const float*)d_in[19];
    const float* n1_b = (const float*)d_in[20];
    const float* r2_w = (const float*)d_in[21];
    const float* r2_q = (const float*)d_in[22];
    const float* r2_k = (const float*)d_in[23];
    const float* r2_b = (const float*)d_in[24];
    const float* n2_w = (const float*)d_in[25];
    const float* n2_b = (const float*)d_in[26];
    const float* c_w1 = (const float*)d_in[27];
    const float* c_b1 = (const float*)d_in[28];
    const float* c_w2 = (const float*)d_in[29];
    const float* c_b2 = (const float*)d_in[30];
    const int* ei_o  = (const int*)d_in[31];
    const int* ei_a  = (const int*)d_in[32];
    const int* ei_s  = (const int*)d_in[33];
    const int* batch = (const int*)d_in[34];
    float* out = (float*)d_out;

    char* p = (char*)d_ws;
    auto alloc = [&](size_t bytes) { char* r = p; p += (bytes + 255) & ~(size_t)255; return r; };
    unsigned short* hbA = (unsigned short*)alloc((size_t)NN * FF * 2);
    unsigned short* hbB = (unsigned short*)alloc((size_t)NN * FF * 2);
    unsigned short* ybuf = (unsigned short*)alloc((size_t)NN * FF * 2);
    unsigned short* xt = (unsigned short*)alloc((size_t)3 * NN * FF * 2);
    unsigned short* wt1 = (unsigned short*)alloc((size_t)3 * FF * FF * 2);
    unsigned short* wt2 = (unsigned short*)alloc((size_t)3 * FF * FF * 2);
    unsigned short* wtv = (unsigned short*)alloc((size_t)1024 * 128 * 2);
    unsigned short* wtc = (unsigned short*)alloc((size_t)FF * 128 * 2);
    float* qkbuf = (float*)alloc((size_t)NN * 48 * 4);
    unsigned short* wqkt1 = (unsigned short*)alloc((size_t)48 * FF * 2);
    unsigned short* wqkt2 = (unsigned short*)alloc((size_t)48 * FF * 2);
    float* t128 = (float*)alloc((size_t)NN * 128 * 4);
    int* rps = (int*)alloc(NN * 4);
    int* elist = (int*)alloc(ETOT * 4);
    float* est = (float*)alloc(64);
    float* pbuf = (float*)alloc(ERB * 6 * 4);
    // ---- contiguous zero-init region (one memset) ----
    char* z0 = alloc((size_t)2 * NN * 4 + 256 + (size_t)4 * GG * 4 + GG * 4);
    int* deg = (int*)z0;
    int* fill = deg + NN;
    int* counter = (int*)(z0 + (size_t)2 * NN * 4);
    float* gs = (float*)(z0 + (size_t)2 * NN * 4 + 256);        // 4*GG: layer1 s1,s2 | layer2 s1,s2
    float* gcnt = gs + 4 * GG;
    hipMemsetAsync(z0, 0, (size_t)2 * NN * 4 + 256 + (size_t)4 * GG * 4 + GG * 4, stream);

    // ---- CSR build + per-graph node counts ----
    csr_count<<<ETOT / 256, 256, 0, stream>>>(ei_o, ei_a, ei_s, deg);
    csr_alloc<<<NN / 256, 256, 0, stream>>>(deg, counter, rps, batch, gcnt);
    csr_fill<<<ETOT / 256, 256, 0, stream>>>(ei_o, ei_a, ei_s, rps, fill, elist);

    // ---- all weight prep up front ----
    transpose2_bf<<<(6 * FF * FF + 255) / 256, 256, 0, stream>>>(r1_w, r2_w, wt1, wt2);
    wqk_prep2<<<dim3(3, 6, 2), 256, 0, stream>>>(r1_w, r1_q, r1_k, r2_w, r2_q, r2_k, wqkt1, wqkt2);
    transpose_bf<<<(1024 * 128 + 255) / 256, 256, 0, stream>>>(vis_w, wtv, 1024, 128, 1024 * 128);
    transpose_bf<<<(FF * 128 + 255) / 256, 256, 0, stream>>>(c_w1, wtc, FF, 128, FF * 128);

    // ---- encoders (all-bf16 h) ----
    gemm_mfma<1, false, true><<<dim3(384, 1, 1), 256, 0, stream>>>(
        x_visual, 1024, wtv, vis_b, hbA, FF, 0, 0);
    gemm_k2_enc<<<dim3(2, 768, 2), 256, 0, stream>>>(
        x_geom, geom_w, geom_b, x_prior, prior_w, prior_b, hbA);
    enc_reduce_stage1<<<ERB, 256, 0, stream>>>(hbA, pbuf);
    enc_reduce_stage2<<<1, 64, 0, stream>>>(pbuf, est);
    enc_apply<<<(int)((size_t)NN * FF / 256), 256, 0, stream>>>(
        hbA, est, vis_lw, vis_lb, geom_lw, geom_lb, prior_lw, prior_lb);

    // ---- RGAT layers (bf16 ping-pong hbA -> hbB -> hbA) ----
    rgat_layer(stream, hbA, r1_b, n1_w, n1_b, rps, deg, elist, batch,
               wt1, xt, wqkt1, qkbuf, gs, gcnt, ybuf, hbB);
    rgat_layer(stream, hbB, r2_b, n2_w, n2_b, rps, deg, elist, batch,
               wt2, xt, wqkt2, qkbuf, gs + 2 * GG, gcnt, ybuf, hbA);

    // ---- classifier ----
    gemm_mfma<1, true, false><<<dim3(384, 1, 1), 256, 0, stream>>>(
        hbA, FF, wtc, c_b1, t128, 128, 0, 0);
    gemm_k<0, false><<<dim3(1, 768, 1), 256, 0, stream>>>(t128, 128, c_w2, 49, c_b2, out, 49, 49);
}